// Round 20
// baseline (460.244 us; speedup 1.0000x reference)
//
#include <hip/hip_runtime.h>
#include <cstdint>

#define TPB 256

typedef __attribute__((ext_vector_type(8))) short s16x8;
typedef __attribute__((ext_vector_type(4))) short s16x4;
typedef __attribute__((ext_vector_type(4))) float f32x4;

__device__ __forceinline__ float silu_f(float x) { return x / (1.f + __expf(-x)); }

__device__ __forceinline__ short f2bf(float f) {
  union { float f; unsigned u; } v; v.f = f;
  unsigned r = v.u + 0x7fffu + ((v.u >> 16) & 1u);
  return (short)(r >> 16);
}
__device__ __forceinline__ float bf2f(short s) {
  union { unsigned u; float f; } v;
  v.u = ((unsigned)(unsigned short)s) << 16;
  return v.f;
}

// All conv weights -> MFMA A-fragment order (bf16), one kernel.  (math verified R3)
__global__ void k_prep_all(const float* __restrict__ w1, const float* __restrict__ w3,
                           const float* __restrict__ w4, const float* __restrict__ wco,
                           const float* __restrict__ wdcn, short* __restrict__ dst) {
  int idx = blockIdx.x * TPB + threadIdx.x;
  if (idx >= 1966080) return;
  const float* w; int Cout, Cin, taps, mode; int local = idx;
  if (idx < 131072)       { w = w1;   Cout = 256; Cin = 512; taps = 1; mode = 0; }
  else if (idx < 196608)  { w = w3;   local -= 131072;  Cout = 256; Cin = 256; taps = 1; mode = 0; }
  else if (idx < 786432)  { w = w4;   local -= 196608;  Cout = 256; Cin = 256; taps = 9; mode = 0; }
  else if (idx < 1376256) { w = wco;  local -= 786432;  Cout = 216; Cin = 256; taps = 9; mode = 0; }
  else                    { w = wdcn; local -= 1376256; Cout = 256; Cin = 256; taps = 9; mode = 1; }
  int j = local & 7;
  int l = (local >> 3) & 63;
  int ot = (local >> 9) & 15;
  int q = local >> 13;
  int tap, cb;
  if (mode == 0) { int ncb = Cin >> 5; tap = q / ncb; cb = q - tap * ncb; }
  else           { tap = q % 9; cb = q / 9; }
  int o = ot * 16 + (l & 15);
  int c = cb * 32 + ((l >> 4) & 3) * 8 + j;
  float v = 0.f;
  if (o < Cout && c < Cin) v = w[((size_t)o * Cin + c) * taps + tap];
  dst[idx] = f2bf(v);
}

// bilinear 16x16 -> 64x64 (half-pixel, edge clamp), write NHWC-512 channels 0..255
__global__ void k_upsample_nhwc(const float* __restrict__ in, short* __restrict__ outA) {
  int idx = blockIdx.x * TPB + threadIdx.x;
  if (idx >= 8 * 4096 * 256) return;
  int c = idx & 255;
  int p = idx >> 8;          // (b*4096 + y*64 + x)
  int b = p >> 12;
  int rem = p & 4095;
  int y = rem >> 6, x = rem & 63;
  float sy = (y + 0.5f) * 0.25f - 0.5f;
  float sx = (x + 0.5f) * 0.25f - 0.5f;
  float y0f = floorf(sy), x0f = floorf(sx);
  float ly = sy - y0f, lx = sx - x0f;
  int y0 = (int)y0f, x0 = (int)x0f;
  int y0c = min(15, max(0, y0)), y1c = min(15, max(0, y0 + 1));
  int x0c = min(15, max(0, x0)), x1c = min(15, max(0, x0 + 1));
  const float* src = in + (size_t)(b * 256 + c) * 256;
  float v00 = src[y0c * 16 + x0c], v01 = src[y0c * 16 + x1c];
  float v10 = src[y1c * 16 + x0c], v11 = src[y1c * 16 + x1c];
  float r = (1.f - ly) * ((1.f - lx) * v00 + lx * v01)
          + ly * ((1.f - lx) * v10 + lx * v11);
  outA[(size_t)p * 512 + c] = f2bf(r);
}

// main f32 NCHW -> bf16 NHWC-256 (xbf) + NHWC-512 ch 256..511 (conv1 input).
__global__ __launch_bounds__(256) void k_main_tr(const float* __restrict__ in,
    short* __restrict__ xbf, short* __restrict__ outA) {
  const int pc = blockIdx.x, ck = blockIdx.y, b = blockIdx.z;
  __shared__ float sl[32][66];
  const int t = threadIdx.x;
  const int pxl = t & 63, cs = t >> 6;
  const float* src = in + (size_t)(b * 256 + ck * 32) * 4096 + pc * 64;
  #pragma unroll
  for (int i = 0; i < 8; ++i) {
    int c = i * 4 + cs;
    sl[c][pxl] = src[(size_t)c * 4096 + pxl];
  }
  __syncthreads();
  const int oct = (t & 3) * 8, px2 = t >> 2;
  s16x8 v;
  #pragma unroll
  for (int j = 0; j < 8; ++j) v[j] = f2bf(sl[oct + j][px2]);
  size_t p = (size_t)b * 4096 + pc * 64 + px2;
  *(s16x8*)(xbf + p * 256 + ck * 32 + oct) = v;
  *(s16x8*)(outA + p * 512 + 256 + ck * 32 + oct) = v;
}

// NHWC MFMA conv, 2-row blocks, XCD-swizzled 1D grid (b = gid&7).
// gab != nullptr: apply per-(b,c) GN affine + SiLU during staging (in-bounds
// only; zero-pad stays 0, matching post-activation conv padding).
__global__ __launch_bounds__(256) void k_conv2(
    const short* __restrict__ in, int Cin, int Cout, int taps,
    const short* __restrict__ wf, const float* __restrict__ bias,
    short* __restrict__ out, int remap, const float2* __restrict__ gab) {
  const int gid = blockIdx.x;
  const int b = gid & 7;
  const int r = gid >> 3;
  const int og = r & 3, yt = r >> 2;
  const int t = threadIdx.x;
  const int wid = t >> 6, l = t & 63;
  const int wo = wid >> 1, wr = wid & 1;
  const int pd = (taps == 9) ? 1 : 0;
  const int rows_in = 2 + 2 * pd;              // 2 or 4
  const int pxw = 64 + 2 * pd;                 // 64 or 66
  const int ncb = Cin >> 5;
  const int nchunk = Cin >> 6;
  const int ndy = (taps == 9) ? 3 : 1;
  __shared__ __align__(16) short sl[4 * 66 * 68];
  f32x4 acc[2][4];
  #pragma unroll
  for (int i = 0; i < 2; ++i)
    #pragma unroll
    for (int j = 0; j < 4; ++j) acc[i][j] = (f32x4){0.f, 0.f, 0.f, 0.f};
  const int y0g = yt * 2 - pd;                 // global row of LDS row 0
  for (int chunk = 0; chunk < nchunk; ++chunk) {
    __syncthreads();
    {
      const int nun = rows_in * pxw * 8;       // s16x8 units (max 2112)
      const int c0 = chunk * 64;
      #pragma unroll
      for (int i = 0; i < 9; ++i) {
        int e = t + i * 256;
        if (e < nun) {
          int oct = e & 7;
          int pe = e >> 3;
          int pxs = pe % pxw;
          int row = pe / pxw;
          int yy = y0g + row, xx = pxs - pd;
          s16x8 v = {0, 0, 0, 0, 0, 0, 0, 0};
          if (yy >= 0 && yy < 64 && xx >= 0 && xx < 64) {
            v = *(const s16x8*)(in + (size_t)((b * 64 + yy) * 64 + xx) * Cin
                                + c0 + oct * 8);
            if (gab) {
              const float2* gp = gab + b * 256 + c0 + oct * 8;
              #pragma unroll
              for (int j = 0; j < 8; ++j) {
                float2 ab = gp[j];
                v[j] = f2bf(silu_f(bf2f(v[j]) * ab.x + ab.y));
              }
            }
          }
          *(s16x8*)(sl + (row * 66 + pxs) * 68 + oct * 8) = v;
        }
      }
    }
    __syncthreads();
    #pragma unroll 2
    for (int cb = 0; cb < 2; ++cb) {
      const int qc = chunk * 2 + cb;
      for (int dyi = 0; dyi < ndy; ++dyi) {
        const int lrow = wr + dyi;            // LDS row (wr+dy+pd)
        for (int dxi = 0; dxi < ndy; ++dxi) {
          const int tap = (taps == 9) ? dyi * 3 + dxi : 0;
          const int q = tap * ncb + qc;
          s16x8 afr[2];
          #pragma unroll
          for (int i = 0; i < 2; ++i) {
            int ot = og * 4 + wo * 2 + i;
            afr[i] = *(const s16x8*)(wf + (((size_t)q * 16 + ot) * 64 + l) * 8);
          }
          #pragma unroll
          for (int jt = 0; jt < 4; ++jt) {
            int pxi = jt * 16 + (l & 15) + dxi;   // dx+pd = dxi
            s16x8 bfr = *(const s16x8*)(sl + (lrow * 66 + pxi) * 68
                                        + cb * 32 + (l >> 4) * 8);
            #pragma unroll
            for (int i = 0; i < 2; ++i)
              acc[i][jt] = __builtin_amdgcn_mfma_f32_16x16x32_bf16(
                  afr[i], bfr, acc[i][jt], 0, 0, 0);
          }
        }
      }
    }
  }
  const int y = yt * 2 + wr;
  #pragma unroll
  for (int i = 0; i < 2; ++i) {
    #pragma unroll
    for (int jt = 0; jt < 4; ++jt) {
      int px = jt * 16 + (l & 15);
      int obase = og * 64 + wo * 32 + i * 16 + (l >> 4) * 4;
      size_t pbase = (size_t)((b * 64 + y) * 64 + px) * (remap ? 256 : Cout);
      if (!remap) {
        s16x4 r2;
        #pragma unroll
        for (int rr = 0; rr < 4; ++rr) r2[rr] = f2bf(acc[i][jt][rr] + bias[obase + rr]);
        *(s16x4*)(out + pbase + obase) = r2;
      } else {
        #pragma unroll
        for (int rr = 0; rr < 4; ++rr) {
          int o = obase + rr;
          if (o < Cout) {
            int op;
            if (o < 144) op = (o / 18) * 32 + (o % 18);
            else { int jj = o - 144; op = (jj / 9) * 32 + 18 + (jj % 9); }
            out[pbase + op] = f2bf(acc[i][jt][rr] + bias[o]);
          }
        }
      }
    }
  }
}

// GroupNorm stats pass: 2048 1D blocks, XCD-swizzled: b = gid&7, r=gid>>3,
// ck = r&7 (512-px chunk), g = r>>3. Partial sums -> parts[gid*2 + {0,1}].
__global__ __launch_bounds__(256) void k_gn_stats(const short* __restrict__ io,
    float* __restrict__ parts) {
  const int gid = blockIdx.x;
  const int b = gid & 7;
  const int r = gid >> 3;
  const int ck = r & 7, g = r >> 3;
  const int t = threadIdx.x;
  float s = 0.f, sq = 0.f;
  #pragma unroll
  for (int i = 0; i < 2; ++i) {
    int e = ck * 512 + t + i * 256;
    s16x8 v = *(const s16x8*)(io + (size_t)(b * 4096 + e) * 256 + g * 8);
    #pragma unroll
    for (int j = 0; j < 8; ++j) { float f = bf2f(v[j]); s += f; sq += f * f; }
  }
  #pragma unroll
  for (int off = 32; off > 0; off >>= 1) {
    s += __shfl_down(s, off);
    sq += __shfl_down(sq, off);
  }
  __shared__ float ps[4], pq[4];
  const int wv = t >> 6, lane = t & 63;
  if (lane == 0) { ps[wv] = s; pq[wv] = sq; }
  __syncthreads();
  if (t == 0) {
    parts[gid * 2]     = ps[0] + ps[1] + ps[2] + ps[3];
    parts[gid * 2 + 1] = pq[0] + pq[1] + pq[2] + pq[3];
  }
}

// Finalize GN: per (b,c) reduce 8 chunk-partials of group g=c>>3 (identical
// arithmetic/order to gn_apply) -> gab[b*256+c] = {ga, bb}.
__global__ __launch_bounds__(256) void k_gn_fin(const float* __restrict__ parts,
    const float* __restrict__ gamma, const float* __restrict__ beta,
    float2* __restrict__ gab) {
  int idx = blockIdx.x * TPB + threadIdx.x;
  if (idx >= 2048) return;
  const int b = idx >> 8, c = idx & 255, g = c >> 3;
  float S = 0.f, Q = 0.f;
  #pragma unroll
  for (int i = 0; i < 8; ++i) {
    int gid2 = (((g << 3) | i) << 3) | b;
    S += parts[gid2 * 2];
    Q += parts[gid2 * 2 + 1];
  }
  const float mean = S * (1.f / 32768.f);
  const float var = Q * (1.f / 32768.f) - mean * mean;
  const float rs = rsqrtf(var + 1e-6f);
  float ga = gamma[c] * rs;
  float bb = beta[c] - mean * ga;
  gab[idx] = make_float2(ga, bb);
}

// GroupNorm apply + SiLU (used for GN3 only): reduces the 8 chunk-partials of
// (b,g), applies to its 512 px x 8 ch slice in-place + f32 NCHW out.
__global__ __launch_bounds__(256) void k_gn_apply(short* __restrict__ io,
    float* __restrict__ f32out, const float* __restrict__ parts,
    const float* __restrict__ gamma, const float* __restrict__ beta) {
  const int gid = blockIdx.x;
  const int b = gid & 7;
  const int r = gid >> 3;
  const int ck = r & 7, g = r >> 3;
  const int t = threadIdx.x;
  float S = 0.f, Q = 0.f;
  #pragma unroll
  for (int i = 0; i < 8; ++i) {
    int gid2 = (((g << 3) | i) << 3) | b;
    S += parts[gid2 * 2];
    Q += parts[gid2 * 2 + 1];
  }
  const float mean = S * (1.f / 32768.f);
  const float var = Q * (1.f / 32768.f) - mean * mean;
  const float rs = rsqrtf(var + 1e-6f);
  float ga[8], bb[8];
  #pragma unroll
  for (int j = 0; j < 8; ++j) {
    ga[j] = gamma[g * 8 + j] * rs;
    bb[j] = beta[g * 8 + j] - mean * ga[j];
  }
  #pragma unroll
  for (int i = 0; i < 2; ++i) {
    int e = ck * 512 + t + i * 256;
    short* ptr = io + (size_t)(b * 4096 + e) * 256 + g * 8;
    s16x8 v = *(const s16x8*)ptr;
    s16x8 r2;
    #pragma unroll
    for (int j = 0; j < 8; ++j) {
      float o = silu_f(bf2f(v[j]) * ga[j] + bb[j]);
      r2[j] = f2bf(o);
      if (f32out) f32out[(size_t)(b * 256 + g * 8 + j) * 4096 + e] = o;
    }
    *(s16x8*)ptr = r2;
  }
}

// depthwise 7x7 pad 3, NHWC bf16, LDS-staged, XCD-swizzled 1D grid.
// gab: GN affine+SiLU applied at staging (in-bounds only).
__global__ __launch_bounds__(256) void k_dw7_nhwc(const short* __restrict__ in,
    const float* __restrict__ w, const float* __restrict__ bias,
    short* __restrict__ out, const float2* __restrict__ gab) {
  const int gid = blockIdx.x;
  const int b = gid & 7;
  const int r = gid >> 3;
  const int ck = r & 7, yt = r >> 3;
  const int t = threadIdx.x;
  const int px = t & 63, oc = t >> 6;
  __shared__ __align__(16) short sl[10 * 70 * 40];
  __shared__ float wl[49 * 32];
  for (int e = t; e < 49 * 32; e += TPB) {
    int tap = e >> 5, cc = e & 31;
    wl[tap * 32 + cc] = w[(ck * 32 + cc) * 49 + tap];
  }
  const int y0in = yt * 4 - 3;
  #pragma unroll
  for (int i = 0; i < 11; ++i) {
    int e = t + i * TPB;
    if (e < 2800) {
      int oc2 = e & 3;
      int pe = e >> 2;
      int pxs = pe % 70;
      int row = pe / 70;
      int yy = y0in + row, xx = pxs - 3;
      s16x8 v = {0, 0, 0, 0, 0, 0, 0, 0};
      if (yy >= 0 && yy < 64 && xx >= 0 && xx < 64) {
        v = *(const s16x8*)(in + (size_t)((b * 64 + yy) * 64 + xx) * 256
                            + ck * 32 + oc2 * 8);
        const float2* gp = gab + b * 256 + ck * 32 + oc2 * 8;
        #pragma unroll
        for (int j = 0; j < 8; ++j) {
          float2 ab = gp[j];
          v[j] = f2bf(silu_f(bf2f(v[j]) * ab.x + ab.y));
        }
      }
      *(s16x8*)(sl + (row * 70 + pxs) * 40 + oc2 * 8) = v;
    }
  }
  __syncthreads();
  float acc[4][8];
  {
    float4 b0 = *(const float4*)(bias + ck * 32 + oc * 8);
    float4 b1 = *(const float4*)(bias + ck * 32 + oc * 8 + 4);
    #pragma unroll
    for (int r2 = 0; r2 < 4; ++r2) {
      acc[r2][0] = b0.x; acc[r2][1] = b0.y; acc[r2][2] = b0.z; acc[r2][3] = b0.w;
      acc[r2][4] = b1.x; acc[r2][5] = b1.y; acc[r2][6] = b1.z; acc[r2][7] = b1.w;
    }
  }
  #pragma unroll
  for (int ky = 0; ky < 7; ++ky) {
    #pragma unroll
    for (int kx = 0; kx < 7; ++kx) {
      const float4 w0 = *(const float4*)(wl + (ky * 7 + kx) * 32 + oc * 8);
      const float4 w1 = *(const float4*)(wl + (ky * 7 + kx) * 32 + oc * 8 + 4);
      #pragma unroll
      for (int r2 = 0; r2 < 4; ++r2) {
        s16x8 v = *(const s16x8*)(sl + ((r2 + ky) * 70 + (px + kx)) * 40 + oc * 8);
        acc[r2][0] += bf2f(v[0]) * w0.x; acc[r2][1] += bf2f(v[1]) * w0.y;
        acc[r2][2] += bf2f(v[2]) * w0.z; acc[r2][3] += bf2f(v[3]) * w0.w;
        acc[r2][4] += bf2f(v[4]) * w1.x; acc[r2][5] += bf2f(v[5]) * w1.y;
        acc[r2][6] += bf2f(v[6]) * w1.z; acc[r2][7] += bf2f(v[7]) * w1.w;
      }
    }
  }
  #pragma unroll
  for (int r2 = 0; r2 < 4; ++r2) {
    int y = yt * 4 + r2;
    s16x8 o;
    #pragma unroll
    for (int j = 0; j < 8; ++j) o[j] = f2bf(acc[r2][j]);
    *(s16x8*)(out + (size_t)((b * 64 + y) * 64 + px) * 256 + ck * 32 + oc * 8) = o;
  }
}

// Deformable conv v2 via MFMA, NHWC, px-split, XCD-swizzled (b = gid&7).
// Phase A: per-(px,k) bilinear weights/addresses once -> LDS table (9-stride).
// Phase B: gather+blend. Phase C: MFMA. (R19 verified, 134us.)
__global__ __launch_bounds__(256) void k_dcn_nhwc(const short* __restrict__ x,
    const short* __restrict__ co, const short* __restrict__ wf,
    const float* __restrict__ bias, float* __restrict__ out) {
  const int gid = blockIdx.x;
  const int b = gid & 7;
  const int r = gid >> 3;
  const int ph = r & 1, y = r >> 1;
  const int t = threadIdx.x;
  const int wid = t >> 6, l = t & 63;
  const int px0 = ph * 32;
  __shared__ __align__(16) short s2[9 * 32 * 40];
  __shared__ unsigned swt[288 * 9];   // [k*32+pxl]: w00..w11 (f32 bits), i00..i11
  f32x4 acc[4][2];
  #pragma unroll
  for (int i = 0; i < 4; ++i)
    #pragma unroll
    for (int j = 0; j < 2; ++j) acc[i][j] = (f32x4){0.f, 0.f, 0.f, 0.f};
  const short* xb = x + (size_t)b * 4096 * 256;
  for (int g = 0; g < 8; ++g) {
    __syncthreads();
    // phase A: 288 dense weight/address tasks (pxl, k)
    #pragma unroll
    for (int i = 0; i < 2; ++i) {
      int e2 = t + i * 256;
      if (e2 < 288) {
        int pxl = e2 & 31, k = e2 >> 5;
        int px = px0 + pxl;
        const short* cp = co + (size_t)(b * 4096 + y * 64 + px) * 256 + g * 32;
        float offy = bf2f(cp[2 * k]);
        float offx = bf2f(cp[2 * k + 1]);
        float mlog = bf2f(cp[18 + k]);
        float mv = 1.f / (1.f + __expf(-mlog));
        float py = offy + (float)(y - 1 + k / 3);
        float pxf = offx + (float)(px - 1 + k % 3);
        float y0f = floorf(py), x0f = floorf(pxf);
        float ly = py - y0f, lx = pxf - x0f;
        int y0 = (int)y0f, x0 = (int)x0f;
        int y1 = y0 + 1, x1 = x0 + 1;
        float fy0 = (y0 >= 0 && y0 < 64) ? 1.f : 0.f;
        float fy1 = (y1 >= 0 && y1 < 64) ? 1.f : 0.f;
        float fx0 = (x0 >= 0 && x0 < 64) ? 1.f : 0.f;
        float fx1 = (x1 >= 0 && x1 < 64) ? 1.f : 0.f;
        float w00 = (1.f - ly) * (1.f - lx) * fy0 * fx0 * mv;
        float w01 = (1.f - ly) * lx * fy0 * fx1 * mv;
        float w10 = ly * (1.f - lx) * fy1 * fx0 * mv;
        float w11 = ly * lx * fy1 * fx1 * mv;
        int y0c = min(63, max(0, y0)), y1c = min(63, max(0, y1));
        int x0c = min(63, max(0, x0)), x1c = min(63, max(0, x1));
        unsigned* wp = swt + e2 * 9;
        wp[0] = __float_as_uint(w00);
        wp[1] = __float_as_uint(w01);
        wp[2] = __float_as_uint(w10);
        wp[3] = __float_as_uint(w11);
        wp[4] = (unsigned)((y0c * 64 + x0c) * 256);
        wp[5] = (unsigned)((y0c * 64 + x1c) * 256);
        wp[6] = (unsigned)((y1c * 64 + x0c) * 256);
        wp[7] = (unsigned)((y1c * 64 + x1c) * 256);
      }
    }
    __syncthreads();
    // phase B: 1152 sampling tasks = 4 oct x 32 px x 9 k (gather + blend)
    #pragma unroll
    for (int i = 0; i < 5; ++i) {
      int e = t + i * 256;
      if (e < 1152) {
        int oct = e & 3, pxl = (e >> 2) & 31, k = e >> 7;
        const unsigned* wp = swt + (k * 32 + pxl) * 9;
        float w00 = __uint_as_float(wp[0]);
        float w01 = __uint_as_float(wp[1]);
        float w10 = __uint_as_float(wp[2]);
        float w11 = __uint_as_float(wp[3]);
        const short* xc = xb + g * 32 + oct * 8;
        s16x8 c00 = *(const s16x8*)(xc + wp[4]);
        s16x8 c01 = *(const s16x8*)(xc + wp[5]);
        s16x8 c10 = *(const s16x8*)(xc + wp[6]);
        s16x8 c11 = *(const s16x8*)(xc + wp[7]);
        s16x8 pk;
        #pragma unroll
        for (int cc = 0; cc < 8; ++cc) {
          float v = w00 * bf2f(c00[cc]) + w01 * bf2f(c01[cc])
                  + w10 * bf2f(c10[cc]) + w11 * bf2f(c11[cc]);
          pk[cc] = f2bf(v);
        }
        *(s16x8*)(s2 + (k * 32 + pxl) * 40 + oct * 8) = pk;
      }
    }
    __syncthreads();
    // phase C: MFMA (unchanged)
    #pragma unroll
    for (int k = 0; k < 9; ++k) {
      const int q = g * 9 + k;
      s16x8 afr[4], bfr[2];
      #pragma unroll
      for (int i = 0; i < 4; ++i)
        afr[i] = *(const s16x8*)(wf + (((size_t)q * 16 + wid * 4 + i) * 64 + l) * 8);
      #pragma unroll
      for (int jt = 0; jt < 2; ++jt)
        bfr[jt] = *(const s16x8*)(s2 + (k * 32 + jt * 16 + (l & 15)) * 40 + (l >> 4) * 8);
      #pragma unroll
      for (int i = 0; i < 4; ++i)
        #pragma unroll
        for (int jt = 0; jt < 2; ++jt)
          acc[i][jt] = __builtin_amdgcn_mfma_f32_16x16x32_bf16(
              afr[i], bfr[jt], acc[i][jt], 0, 0, 0);
    }
  }
  #pragma unroll
  for (int i = 0; i < 4; ++i) {
    int obase = wid * 64 + i * 16 + (l >> 4) * 4;
    #pragma unroll
    for (int jt = 0; jt < 2; ++jt) {
      int pxo = px0 + jt * 16 + (l & 15);
      #pragma unroll
      for (int rr = 0; rr < 4; ++rr) {
        int o = obase + rr;
        out[(((size_t)b * 256 + o) * 64 + y) * 64 + pxo] = acc[i][jt][rr] + bias[o];
      }
    }
  }
}

extern "C" void kernel_launch(void* const* d_in, const int* in_sizes, int n_in,
                              void* d_out, int out_size, void* d_ws, size_t ws_size,
                              hipStream_t stream) {
  const float* main_f = (const float*)d_in[0];
  const float* cond   = (const float*)d_in[1];
  const float* w1  = (const float*)d_in[2];
  const float* b1  = (const float*)d_in[3];
  const float* g1  = (const float*)d_in[4];
  const float* be1 = (const float*)d_in[5];
  const float* w2  = (const float*)d_in[6];
  const float* b2  = (const float*)d_in[7];
  const float* g2  = (const float*)d_in[8];
  const float* be2 = (const float*)d_in[9];
  const float* w3  = (const float*)d_in[10];
  const float* b3  = (const float*)d_in[11];
  const float* w4  = (const float*)d_in[12];
  const float* b4  = (const float*)d_in[13];
  const float* g3  = (const float*)d_in[14];
  const float* be3 = (const float*)d_in[15];
  const float* w_co  = (const float*)d_in[16];
  const float* b_co  = (const float*)d_in[17];
  const float* w_dcn = (const float*)d_in[18];
  const float* b_dcn = (const float*)d_in[19];

  float* out = (float*)d_out;
  float* warp_out = out;               // [8,256,64,64] f32 NCHW
  float* offset_feat = out + 8388608;  // [8,256,64,64] f32 NCHW

  short* ws = (short*)d_ws;
  short* bufA  = ws;                   // NHWC-512 conv1 input: 16777216
  short* Bb    = bufA + 16777216;      // NHWC-256: 8388608
  short* xbf   = Bb + 8388608;         // main NHWC-256 bf16: 8388608
  short* wfall = xbf + 8388608;        // contiguous: wf1 wf3 wf4 wfco wfdcn
  short* wf1   = wfall;                // 131072
  short* wf3   = wf1 + 131072;         // 65536
  short* wf4   = wf3 + 65536;          // 589824
  short* wfco  = wf4 + 589824;         // 589824
  short* wfdcn = wfco + 589824;        // 589824
  float* gparts = (float*)(wfdcn + 589824);  // 2048*2 f32
  float2* gab   = (float2*)(gparts + 4096);  // 2048 float2

  auto cdiv = [](int a, int b) { return (a + b - 1) / b; };

  k_prep_all<<<cdiv(1966080, TPB), TPB, 0, stream>>>(w1, w3, w4, w_co, w_dcn, wfall);

  k_upsample_nhwc<<<cdiv(8 * 4096 * 256, TPB), TPB, 0, stream>>>(cond, bufA);
  dim3 gtr(64, 8, 8);
  k_main_tr<<<gtr, TPB, 0, stream>>>(main_f, xbf, bufA);

  // conv1: 1x1 NHWC-512 -> NHWC-256 (raw output; GN1 fused into dw7 staging)
  k_conv2<<<1024, TPB, 0, stream>>>(bufA, 512, 256, 1, wf1, b1, Bb, 0, nullptr);
  k_gn_stats<<<2048, TPB, 0, stream>>>(Bb, gparts);
  k_gn_fin<<<8, TPB, 0, stream>>>(gparts, g1, be1, gab);
  k_dw7_nhwc<<<1024, TPB, 0, stream>>>(Bb, w2, b2, bufA, gab);
  k_gn_stats<<<2048, TPB, 0, stream>>>(bufA, gparts);
  k_gn_fin<<<8, TPB, 0, stream>>>(gparts, g2, be2, gab);
  // conv3: 1x1 with fused GN2 apply at staging
  k_conv2<<<1024, TPB, 0, stream>>>(bufA, 256, 256, 1, wf3, b3, Bb, 0, gab);
  // conv4: 3x3
  k_conv2<<<1024, TPB, 0, stream>>>(Bb, 256, 256, 9, wf4, b4, bufA, 0, nullptr);
  // GN3 + SiLU (3 consumers + f32 output -> keep standalone apply)
  k_gn_stats<<<2048, TPB, 0, stream>>>(bufA, gparts);
  k_gn_apply<<<2048, TPB, 0, stream>>>(bufA, offset_feat, gparts, g3, be3);
  // conv_offset: 3x3 256->216, channel-permuted NHWC-256 co
  k_conv2<<<1024, TPB, 0, stream>>>(bufA, 256, 216, 9, wfco, b_co, Bb, 1, nullptr);
  // deformable conv -> warp (output 0)
  k_dcn_nhwc<<<1024, TPB, 0, stream>>>(xbf, Bb, wfdcn, b_dcn, warp_out);
}

// Round 21
// 454.602 us; speedup vs baseline: 1.0124x; 1.0124x over previous
//
#include <hip/hip_runtime.h>
#include <cstdint>

#define TPB 256

typedef __attribute__((ext_vector_type(8))) short s16x8;
typedef __attribute__((ext_vector_type(4))) short s16x4;
typedef __attribute__((ext_vector_type(4))) float f32x4;

__device__ __forceinline__ float silu_f(float x) { return x / (1.f + __expf(-x)); }

__device__ __forceinline__ short f2bf(float f) {
  union { float f; unsigned u; } v; v.f = f;
  unsigned r = v.u + 0x7fffu + ((v.u >> 16) & 1u);
  return (short)(r >> 16);
}
__device__ __forceinline__ float bf2f(short s) {
  union { unsigned u; float f; } v;
  v.u = ((unsigned)(unsigned short)s) << 16;
  return v.f;
}

// All conv weights -> MFMA A-fragment order (bf16), one kernel.  (math verified R3)
__global__ void k_prep_all(const float* __restrict__ w1, const float* __restrict__ w3,
                           const float* __restrict__ w4, const float* __restrict__ wco,
                           const float* __restrict__ wdcn, short* __restrict__ dst) {
  int idx = blockIdx.x * TPB + threadIdx.x;
  if (idx >= 1966080) return;
  const float* w; int Cout, Cin, taps, mode; int local = idx;
  if (idx < 131072)       { w = w1;   Cout = 256; Cin = 512; taps = 1; mode = 0; }
  else if (idx < 196608)  { w = w3;   local -= 131072;  Cout = 256; Cin = 256; taps = 1; mode = 0; }
  else if (idx < 786432)  { w = w4;   local -= 196608;  Cout = 256; Cin = 256; taps = 9; mode = 0; }
  else if (idx < 1376256) { w = wco;  local -= 786432;  Cout = 216; Cin = 256; taps = 9; mode = 0; }
  else                    { w = wdcn; local -= 1376256; Cout = 256; Cin = 256; taps = 9; mode = 1; }
  int j = local & 7;
  int l = (local >> 3) & 63;
  int ot = (local >> 9) & 15;
  int q = local >> 13;
  int tap, cb;
  if (mode == 0) { int ncb = Cin >> 5; tap = q / ncb; cb = q - tap * ncb; }
  else           { tap = q % 9; cb = q / 9; }
  int o = ot * 16 + (l & 15);
  int c = cb * 32 + ((l >> 4) & 3) * 8 + j;
  float v = 0.f;
  if (o < Cout && c < Cin) v = w[((size_t)o * Cin + c) * taps + tap];
  dst[idx] = f2bf(v);
}

// bilinear 16x16 -> 64x64 (half-pixel, edge clamp), write NHWC-512 channels 0..255
__global__ void k_upsample_nhwc(const float* __restrict__ in, short* __restrict__ outA) {
  int idx = blockIdx.x * TPB + threadIdx.x;
  if (idx >= 8 * 4096 * 256) return;
  int c = idx & 255;
  int p = idx >> 8;          // (b*4096 + y*64 + x)
  int b = p >> 12;
  int rem = p & 4095;
  int y = rem >> 6, x = rem & 63;
  float sy = (y + 0.5f) * 0.25f - 0.5f;
  float sx = (x + 0.5f) * 0.25f - 0.5f;
  float y0f = floorf(sy), x0f = floorf(sx);
  float ly = sy - y0f, lx = sx - x0f;
  int y0 = (int)y0f, x0 = (int)x0f;
  int y0c = min(15, max(0, y0)), y1c = min(15, max(0, y0 + 1));
  int x0c = min(15, max(0, x0)), x1c = min(15, max(0, x0 + 1));
  const float* src = in + (size_t)(b * 256 + c) * 256;
  float v00 = src[y0c * 16 + x0c], v01 = src[y0c * 16 + x1c];
  float v10 = src[y1c * 16 + x0c], v11 = src[y1c * 16 + x1c];
  float r = (1.f - ly) * ((1.f - lx) * v00 + lx * v01)
          + ly * ((1.f - lx) * v10 + lx * v11);
  outA[(size_t)p * 512 + c] = f2bf(r);
}

// main f32 NCHW -> bf16 NHWC-256 (xbf) + NHWC-512 ch 256..511 (conv1 input).
__global__ __launch_bounds__(256) void k_main_tr(const float* __restrict__ in,
    short* __restrict__ xbf, short* __restrict__ outA) {
  const int pc = blockIdx.x, ck = blockIdx.y, b = blockIdx.z;
  __shared__ float sl[32][66];
  const int t = threadIdx.x;
  const int pxl = t & 63, cs = t >> 6;
  const float* src = in + (size_t)(b * 256 + ck * 32) * 4096 + pc * 64;
  #pragma unroll
  for (int i = 0; i < 8; ++i) {
    int c = i * 4 + cs;
    sl[c][pxl] = src[(size_t)c * 4096 + pxl];
  }
  __syncthreads();
  const int oct = (t & 3) * 8, px2 = t >> 2;
  s16x8 v;
  #pragma unroll
  for (int j = 0; j < 8; ++j) v[j] = f2bf(sl[oct + j][px2]);
  size_t p = (size_t)b * 4096 + pc * 64 + px2;
  *(s16x8*)(xbf + p * 256 + ck * 32 + oct) = v;
  *(s16x8*)(outA + p * 512 + 256 + ck * 32 + oct) = v;
}

// NHWC MFMA conv, 2-row blocks, XCD-swizzled 1D grid (b = gid&7).
// gab != nullptr: apply per-(b,c) GN affine + SiLU during staging (in-bounds
// only; zero-pad stays 0, matching post-activation conv padding).
__global__ __launch_bounds__(256) void k_conv2(
    const short* __restrict__ in, int Cin, int Cout, int taps,
    const short* __restrict__ wf, const float* __restrict__ bias,
    short* __restrict__ out, int remap, const float2* __restrict__ gab) {
  const int gid = blockIdx.x;
  const int b = gid & 7;
  const int r = gid >> 3;
  const int og = r & 3, yt = r >> 2;
  const int t = threadIdx.x;
  const int wid = t >> 6, l = t & 63;
  const int wo = wid >> 1, wr = wid & 1;
  const int pd = (taps == 9) ? 1 : 0;
  const int rows_in = 2 + 2 * pd;              // 2 or 4
  const int pxw = 64 + 2 * pd;                 // 64 or 66
  const int ncb = Cin >> 5;
  const int nchunk = Cin >> 6;
  const int ndy = (taps == 9) ? 3 : 1;
  __shared__ __align__(16) short sl[4 * 66 * 68];
  f32x4 acc[2][4];
  #pragma unroll
  for (int i = 0; i < 2; ++i)
    #pragma unroll
    for (int j = 0; j < 4; ++j) acc[i][j] = (f32x4){0.f, 0.f, 0.f, 0.f};
  const int y0g = yt * 2 - pd;                 // global row of LDS row 0
  for (int chunk = 0; chunk < nchunk; ++chunk) {
    __syncthreads();
    {
      const int nun = rows_in * pxw * 8;       // s16x8 units (max 2112)
      const int c0 = chunk * 64;
      #pragma unroll
      for (int i = 0; i < 9; ++i) {
        int e = t + i * 256;
        if (e < nun) {
          int oct = e & 7;
          int pe = e >> 3;
          int pxs = pe % pxw;
          int row = pe / pxw;
          int yy = y0g + row, xx = pxs - pd;
          s16x8 v = {0, 0, 0, 0, 0, 0, 0, 0};
          if (yy >= 0 && yy < 64 && xx >= 0 && xx < 64) {
            v = *(const s16x8*)(in + (size_t)((b * 64 + yy) * 64 + xx) * Cin
                                + c0 + oct * 8);
            if (gab) {
              const float2* gp = gab + b * 256 + c0 + oct * 8;
              #pragma unroll
              for (int j = 0; j < 8; ++j) {
                float2 ab = gp[j];
                v[j] = f2bf(silu_f(bf2f(v[j]) * ab.x + ab.y));
              }
            }
          }
          *(s16x8*)(sl + (row * 66 + pxs) * 68 + oct * 8) = v;
        }
      }
    }
    __syncthreads();
    #pragma unroll 2
    for (int cb = 0; cb < 2; ++cb) {
      const int qc = chunk * 2 + cb;
      for (int dyi = 0; dyi < ndy; ++dyi) {
        const int lrow = wr + dyi;            // LDS row (wr+dy+pd)
        for (int dxi = 0; dxi < ndy; ++dxi) {
          const int tap = (taps == 9) ? dyi * 3 + dxi : 0;
          const int q = tap * ncb + qc;
          s16x8 afr[2];
          #pragma unroll
          for (int i = 0; i < 2; ++i) {
            int ot = og * 4 + wo * 2 + i;
            afr[i] = *(const s16x8*)(wf + (((size_t)q * 16 + ot) * 64 + l) * 8);
          }
          #pragma unroll
          for (int jt = 0; jt < 4; ++jt) {
            int pxi = jt * 16 + (l & 15) + dxi;   // dx+pd = dxi
            s16x8 bfr = *(const s16x8*)(sl + (lrow * 66 + pxi) * 68
                                        + cb * 32 + (l >> 4) * 8);
            #pragma unroll
            for (int i = 0; i < 2; ++i)
              acc[i][jt] = __builtin_amdgcn_mfma_f32_16x16x32_bf16(
                  afr[i], bfr, acc[i][jt], 0, 0, 0);
          }
        }
      }
    }
  }
  const int y = yt * 2 + wr;
  #pragma unroll
  for (int i = 0; i < 2; ++i) {
    #pragma unroll
    for (int jt = 0; jt < 4; ++jt) {
      int px = jt * 16 + (l & 15);
      int obase = og * 64 + wo * 32 + i * 16 + (l >> 4) * 4;
      size_t pbase = (size_t)((b * 64 + y) * 64 + px) * (remap ? 256 : Cout);
      if (!remap) {
        s16x4 r2;
        #pragma unroll
        for (int rr = 0; rr < 4; ++rr) r2[rr] = f2bf(acc[i][jt][rr] + bias[obase + rr]);
        *(s16x4*)(out + pbase + obase) = r2;
      } else {
        #pragma unroll
        for (int rr = 0; rr < 4; ++rr) {
          int o = obase + rr;
          if (o < Cout) {
            int op;
            if (o < 144) op = (o / 18) * 32 + (o % 18);
            else { int jj = o - 144; op = (jj / 9) * 32 + 18 + (jj % 9); }
            out[pbase + op] = f2bf(acc[i][jt][rr] + bias[o]);
          }
        }
      }
    }
  }
}

// GroupNorm stats pass: 2048 1D blocks, XCD-swizzled: b = gid&7, r=gid>>3,
// ck = r&7 (512-px chunk), g = r>>3. Partial sums -> parts[gid*2 + {0,1}].
__global__ __launch_bounds__(256) void k_gn_stats(const short* __restrict__ io,
    float* __restrict__ parts) {
  const int gid = blockIdx.x;
  const int b = gid & 7;
  const int r = gid >> 3;
  const int ck = r & 7, g = r >> 3;
  const int t = threadIdx.x;
  float s = 0.f, sq = 0.f;
  #pragma unroll
  for (int i = 0; i < 2; ++i) {
    int e = ck * 512 + t + i * 256;
    s16x8 v = *(const s16x8*)(io + (size_t)(b * 4096 + e) * 256 + g * 8);
    #pragma unroll
    for (int j = 0; j < 8; ++j) { float f = bf2f(v[j]); s += f; sq += f * f; }
  }
  #pragma unroll
  for (int off = 32; off > 0; off >>= 1) {
    s += __shfl_down(s, off);
    sq += __shfl_down(sq, off);
  }
  __shared__ float ps[4], pq[4];
  const int wv = t >> 6, lane = t & 63;
  if (lane == 0) { ps[wv] = s; pq[wv] = sq; }
  __syncthreads();
  if (t == 0) {
    parts[gid * 2]     = ps[0] + ps[1] + ps[2] + ps[3];
    parts[gid * 2 + 1] = pq[0] + pq[1] + pq[2] + pq[3];
  }
}

// Finalize GN: per (b,c) reduce 8 chunk-partials of group g=c>>3 (identical
// arithmetic/order to gn_apply) -> gab[b*256+c] = {ga, bb}.
__global__ __launch_bounds__(256) void k_gn_fin(const float* __restrict__ parts,
    const float* __restrict__ gamma, const float* __restrict__ beta,
    float2* __restrict__ gab) {
  int idx = blockIdx.x * TPB + threadIdx.x;
  if (idx >= 2048) return;
  const int b = idx >> 8, c = idx & 255, g = c >> 3;
  float S = 0.f, Q = 0.f;
  #pragma unroll
  for (int i = 0; i < 8; ++i) {
    int gid2 = (((g << 3) | i) << 3) | b;
    S += parts[gid2 * 2];
    Q += parts[gid2 * 2 + 1];
  }
  const float mean = S * (1.f / 32768.f);
  const float var = Q * (1.f / 32768.f) - mean * mean;
  const float rs = rsqrtf(var + 1e-6f);
  float ga = gamma[c] * rs;
  float bb = beta[c] - mean * ga;
  gab[idx] = make_float2(ga, bb);
}

// GroupNorm apply + SiLU: reduces the 8 chunk-partials of (b,g), applies to
// its 512 px x 8 ch slice in-place (bf16) + optional f32 NCHW out.
__global__ __launch_bounds__(256) void k_gn_apply(short* __restrict__ io,
    float* __restrict__ f32out, const float* __restrict__ parts,
    const float* __restrict__ gamma, const float* __restrict__ beta) {
  const int gid = blockIdx.x;
  const int b = gid & 7;
  const int r = gid >> 3;
  const int ck = r & 7, g = r >> 3;
  const int t = threadIdx.x;
  float S = 0.f, Q = 0.f;
  #pragma unroll
  for (int i = 0; i < 8; ++i) {
    int gid2 = (((g << 3) | i) << 3) | b;
    S += parts[gid2 * 2];
    Q += parts[gid2 * 2 + 1];
  }
  const float mean = S * (1.f / 32768.f);
  const float var = Q * (1.f / 32768.f) - mean * mean;
  const float rs = rsqrtf(var + 1e-6f);
  float ga[8], bb[8];
  #pragma unroll
  for (int j = 0; j < 8; ++j) {
    ga[j] = gamma[g * 8 + j] * rs;
    bb[j] = beta[g * 8 + j] - mean * ga[j];
  }
  #pragma unroll
  for (int i = 0; i < 2; ++i) {
    int e = ck * 512 + t + i * 256;
    short* ptr = io + (size_t)(b * 4096 + e) * 256 + g * 8;
    s16x8 v = *(const s16x8*)ptr;
    s16x8 r2;
    #pragma unroll
    for (int j = 0; j < 8; ++j) {
      float o = silu_f(bf2f(v[j]) * ga[j] + bb[j]);
      r2[j] = f2bf(o);
      if (f32out) f32out[(size_t)(b * 256 + g * 8 + j) * 4096 + e] = o;
    }
    *(s16x8*)ptr = r2;
  }
}

// depthwise 7x7 pad 3, NHWC bf16, LDS-staged, XCD-swizzled 1D grid (unfused:
// halo staging has 2.5x redundancy -> GN fusion here is net-negative, R20).
__global__ __launch_bounds__(256) void k_dw7_nhwc(const short* __restrict__ in,
    const float* __restrict__ w, const float* __restrict__ bias,
    short* __restrict__ out) {
  const int gid = blockIdx.x;
  const int b = gid & 7;
  const int r = gid >> 3;
  const int ck = r & 7, yt = r >> 3;
  const int t = threadIdx.x;
  const int px = t & 63, oc = t >> 6;
  __shared__ __align__(16) short sl[10 * 70 * 40];
  __shared__ float wl[49 * 32];
  for (int e = t; e < 49 * 32; e += TPB) {
    int tap = e >> 5, cc = e & 31;
    wl[tap * 32 + cc] = w[(ck * 32 + cc) * 49 + tap];
  }
  const int y0in = yt * 4 - 3;
  #pragma unroll
  for (int i = 0; i < 11; ++i) {
    int e = t + i * TPB;
    if (e < 2800) {
      int oc2 = e & 3;
      int pe = e >> 2;
      int pxs = pe % 70;
      int row = pe / 70;
      int yy = y0in + row, xx = pxs - 3;
      s16x8 v = {0, 0, 0, 0, 0, 0, 0, 0};
      if (yy >= 0 && yy < 64 && xx >= 0 && xx < 64)
        v = *(const s16x8*)(in + (size_t)((b * 64 + yy) * 64 + xx) * 256
                            + ck * 32 + oc2 * 8);
      *(s16x8*)(sl + (row * 70 + pxs) * 40 + oc2 * 8) = v;
    }
  }
  __syncthreads();
  float acc[4][8];
  {
    float4 b0 = *(const float4*)(bias + ck * 32 + oc * 8);
    float4 b1 = *(const float4*)(bias + ck * 32 + oc * 8 + 4);
    #pragma unroll
    for (int r2 = 0; r2 < 4; ++r2) {
      acc[r2][0] = b0.x; acc[r2][1] = b0.y; acc[r2][2] = b0.z; acc[r2][3] = b0.w;
      acc[r2][4] = b1.x; acc[r2][5] = b1.y; acc[r2][6] = b1.z; acc[r2][7] = b1.w;
    }
  }
  #pragma unroll
  for (int ky = 0; ky < 7; ++ky) {
    #pragma unroll
    for (int kx = 0; kx < 7; ++kx) {
      const float4 w0 = *(const float4*)(wl + (ky * 7 + kx) * 32 + oc * 8);
      const float4 w1 = *(const float4*)(wl + (ky * 7 + kx) * 32 + oc * 8 + 4);
      #pragma unroll
      for (int r2 = 0; r2 < 4; ++r2) {
        s16x8 v = *(const s16x8*)(sl + ((r2 + ky) * 70 + (px + kx)) * 40 + oc * 8);
        acc[r2][0] += bf2f(v[0]) * w0.x; acc[r2][1] += bf2f(v[1]) * w0.y;
        acc[r2][2] += bf2f(v[2]) * w0.z; acc[r2][3] += bf2f(v[3]) * w0.w;
        acc[r2][4] += bf2f(v[4]) * w1.x; acc[r2][5] += bf2f(v[5]) * w1.y;
        acc[r2][6] += bf2f(v[6]) * w1.z; acc[r2][7] += bf2f(v[7]) * w1.w;
      }
    }
  }
  #pragma unroll
  for (int r2 = 0; r2 < 4; ++r2) {
    int y = yt * 4 + r2;
    s16x8 o;
    #pragma unroll
    for (int j = 0; j < 8; ++j) o[j] = f2bf(acc[r2][j]);
    *(s16x8*)(out + (size_t)((b * 64 + y) * 64 + px) * 256 + ck * 32 + oc * 8) = o;
  }
}

// Deformable conv v2 via MFMA, NHWC, px-split, XCD-swizzled (b = gid&7).
// Phase A: per-(px,k) bilinear weights/addresses once -> LDS table (9-stride).
// Phase B: gather+blend. Phase C: MFMA. (R19 verified, 134us.)
__global__ __launch_bounds__(256) void k_dcn_nhwc(const short* __restrict__ x,
    const short* __restrict__ co, const short* __restrict__ wf,
    const float* __restrict__ bias, float* __restrict__ out) {
  const int gid = blockIdx.x;
  const int b = gid & 7;
  const int r = gid >> 3;
  const int ph = r & 1, y = r >> 1;
  const int t = threadIdx.x;
  const int wid = t >> 6, l = t & 63;
  const int px0 = ph * 32;
  __shared__ __align__(16) short s2[9 * 32 * 40];
  __shared__ unsigned swt[288 * 9];   // [k*32+pxl]: w00..w11 (f32 bits), i00..i11
  f32x4 acc[4][2];
  #pragma unroll
  for (int i = 0; i < 4; ++i)
    #pragma unroll
    for (int j = 0; j < 2; ++j) acc[i][j] = (f32x4){0.f, 0.f, 0.f, 0.f};
  const short* xb = x + (size_t)b * 4096 * 256;
  for (int g = 0; g < 8; ++g) {
    __syncthreads();
    // phase A: 288 dense weight/address tasks (pxl, k)
    #pragma unroll
    for (int i = 0; i < 2; ++i) {
      int e2 = t + i * 256;
      if (e2 < 288) {
        int pxl = e2 & 31, k = e2 >> 5;
        int px = px0 + pxl;
        const short* cp = co + (size_t)(b * 4096 + y * 64 + px) * 256 + g * 32;
        float offy = bf2f(cp[2 * k]);
        float offx = bf2f(cp[2 * k + 1]);
        float mlog = bf2f(cp[18 + k]);
        float mv = 1.f / (1.f + __expf(-mlog));
        float py = offy + (float)(y - 1 + k / 3);
        float pxf = offx + (float)(px - 1 + k % 3);
        float y0f = floorf(py), x0f = floorf(pxf);
        float ly = py - y0f, lx = pxf - x0f;
        int y0 = (int)y0f, x0 = (int)x0f;
        int y1 = y0 + 1, x1 = x0 + 1;
        float fy0 = (y0 >= 0 && y0 < 64) ? 1.f : 0.f;
        float fy1 = (y1 >= 0 && y1 < 64) ? 1.f : 0.f;
        float fx0 = (x0 >= 0 && x0 < 64) ? 1.f : 0.f;
        float fx1 = (x1 >= 0 && x1 < 64) ? 1.f : 0.f;
        float w00 = (1.f - ly) * (1.f - lx) * fy0 * fx0 * mv;
        float w01 = (1.f - ly) * lx * fy0 * fx1 * mv;
        float w10 = ly * (1.f - lx) * fy1 * fx0 * mv;
        float w11 = ly * lx * fy1 * fx1 * mv;
        int y0c = min(63, max(0, y0)), y1c = min(63, max(0, y1));
        int x0c = min(63, max(0, x0)), x1c = min(63, max(0, x1));
        unsigned* wp = swt + e2 * 9;
        wp[0] = __float_as_uint(w00);
        wp[1] = __float_as_uint(w01);
        wp[2] = __float_as_uint(w10);
        wp[3] = __float_as_uint(w11);
        wp[4] = (unsigned)((y0c * 64 + x0c) * 256);
        wp[5] = (unsigned)((y0c * 64 + x1c) * 256);
        wp[6] = (unsigned)((y1c * 64 + x0c) * 256);
        wp[7] = (unsigned)((y1c * 64 + x1c) * 256);
      }
    }
    __syncthreads();
    // phase B: 1152 sampling tasks = 4 oct x 32 px x 9 k (gather + blend)
    #pragma unroll
    for (int i = 0; i < 5; ++i) {
      int e = t + i * 256;
      if (e < 1152) {
        int oct = e & 3, pxl = (e >> 2) & 31, k = e >> 7;
        const unsigned* wp = swt + (k * 32 + pxl) * 9;
        float w00 = __uint_as_float(wp[0]);
        float w01 = __uint_as_float(wp[1]);
        float w10 = __uint_as_float(wp[2]);
        float w11 = __uint_as_float(wp[3]);
        const short* xc = xb + g * 32 + oct * 8;
        s16x8 c00 = *(const s16x8*)(xc + wp[4]);
        s16x8 c01 = *(const s16x8*)(xc + wp[5]);
        s16x8 c10 = *(const s16x8*)(xc + wp[6]);
        s16x8 c11 = *(const s16x8*)(xc + wp[7]);
        s16x8 pk;
        #pragma unroll
        for (int cc = 0; cc < 8; ++cc) {
          float v = w00 * bf2f(c00[cc]) + w01 * bf2f(c01[cc])
                  + w10 * bf2f(c10[cc]) + w11 * bf2f(c11[cc]);
          pk[cc] = f2bf(v);
        }
        *(s16x8*)(s2 + (k * 32 + pxl) * 40 + oct * 8) = pk;
      }
    }
    __syncthreads();
    // phase C: MFMA (unchanged)
    #pragma unroll
    for (int k = 0; k < 9; ++k) {
      const int q = g * 9 + k;
      s16x8 afr[4], bfr[2];
      #pragma unroll
      for (int i = 0; i < 4; ++i)
        afr[i] = *(const s16x8*)(wf + (((size_t)q * 16 + wid * 4 + i) * 64 + l) * 8);
      #pragma unroll
      for (int jt = 0; jt < 2; ++jt)
        bfr[jt] = *(const s16x8*)(s2 + (k * 32 + jt * 16 + (l & 15)) * 40 + (l >> 4) * 8);
      #pragma unroll
      for (int i = 0; i < 4; ++i)
        #pragma unroll
        for (int jt = 0; jt < 2; ++jt)
          acc[i][jt] = __builtin_amdgcn_mfma_f32_16x16x32_bf16(
              afr[i], bfr[jt], acc[i][jt], 0, 0, 0);
    }
  }
  #pragma unroll
  for (int i = 0; i < 4; ++i) {
    int obase = wid * 64 + i * 16 + (l >> 4) * 4;
    #pragma unroll
    for (int jt = 0; jt < 2; ++jt) {
      int pxo = px0 + jt * 16 + (l & 15);
      #pragma unroll
      for (int rr = 0; rr < 4; ++rr) {
        int o = obase + rr;
        out[(((size_t)b * 256 + o) * 64 + y) * 64 + pxo] = acc[i][jt][rr] + bias[o];
      }
    }
  }
}

extern "C" void kernel_launch(void* const* d_in, const int* in_sizes, int n_in,
                              void* d_out, int out_size, void* d_ws, size_t ws_size,
                              hipStream_t stream) {
  const float* main_f = (const float*)d_in[0];
  const float* cond   = (const float*)d_in[1];
  const float* w1  = (const float*)d_in[2];
  const float* b1  = (const float*)d_in[3];
  const float* g1  = (const float*)d_in[4];
  const float* be1 = (const float*)d_in[5];
  const float* w2  = (const float*)d_in[6];
  const float* b2  = (const float*)d_in[7];
  const float* g2  = (const float*)d_in[8];
  const float* be2 = (const float*)d_in[9];
  const float* w3  = (const float*)d_in[10];
  const float* b3  = (const float*)d_in[11];
  const float* w4  = (const float*)d_in[12];
  const float* b4  = (const float*)d_in[13];
  const float* g3  = (const float*)d_in[14];
  const float* be3 = (const float*)d_in[15];
  const float* w_co  = (const float*)d_in[16];
  const float* b_co  = (const float*)d_in[17];
  const float* w_dcn = (const float*)d_in[18];
  const float* b_dcn = (const float*)d_in[19];

  float* out = (float*)d_out;
  float* warp_out = out;               // [8,256,64,64] f32 NCHW
  float* offset_feat = out + 8388608;  // [8,256,64,64] f32 NCHW

  short* ws = (short*)d_ws;
  short* bufA  = ws;                   // NHWC-512 conv1 input: 16777216
  short* Bb    = bufA + 16777216;      // NHWC-256: 8388608
  short* xbf   = Bb + 8388608;         // main NHWC-256 bf16: 8388608
  short* wfall = xbf + 8388608;        // contiguous: wf1 wf3 wf4 wfco wfdcn
  short* wf1   = wfall;                // 131072
  short* wf3   = wf1 + 131072;         // 65536
  short* wf4   = wf3 + 65536;          // 589824
  short* wfco  = wf4 + 589824;         // 589824
  short* wfdcn = wfco + 589824;        // 589824
  float* gparts = (float*)(wfdcn + 589824);  // 2048*2 f32
  float2* gab   = (float2*)(gparts + 4096);  // 2048 float2

  auto cdiv = [](int a, int b) { return (a + b - 1) / b; };

  k_prep_all<<<cdiv(1966080, TPB), TPB, 0, stream>>>(w1, w3, w4, w_co, w_dcn, wfall);

  k_upsample_nhwc<<<cdiv(8 * 4096 * 256, TPB), TPB, 0, stream>>>(cond, bufA);
  dim3 gtr(64, 8, 8);
  k_main_tr<<<gtr, TPB, 0, stream>>>(main_f, xbf, bufA);

  // conv1: 1x1 NHWC-512 -> NHWC-256
  k_conv2<<<1024, TPB, 0, stream>>>(bufA, 512, 256, 1, wf1, b1, Bb, 0, nullptr);
  // GN1: standalone apply (dw7 halo staging makes fusion net-negative, R20)
  k_gn_stats<<<2048, TPB, 0, stream>>>(Bb, gparts);
  k_gn_apply<<<2048, TPB, 0, stream>>>(Bb, nullptr, gparts, g1, be1);
  k_dw7_nhwc<<<1024, TPB, 0, stream>>>(Bb, w2, b2, bufA);
  // GN2: fused into conv3 staging (1x1 -> zero halo redundancy)
  k_gn_stats<<<2048, TPB, 0, stream>>>(bufA, gparts);
  k_gn_fin<<<8, TPB, 0, stream>>>(gparts, g2, be2, gab);
  k_conv2<<<1024, TPB, 0, stream>>>(bufA, 256, 256, 1, wf3, b3, Bb, 0, gab);
  // conv4: 3x3
  k_conv2<<<1024, TPB, 0, stream>>>(Bb, 256, 256, 9, wf4, b4, bufA, 0, nullptr);
  // GN3 + SiLU (f32 output + 2 consumers -> standalone apply)
  k_gn_stats<<<2048, TPB, 0, stream>>>(bufA, gparts);
  k_gn_apply<<<2048, TPB, 0, stream>>>(bufA, offset_feat, gparts, g3, be3);
  // conv_offset: 3x3 256->216, channel-permuted NHWC-256 co
  k_conv2<<<1024, TPB, 0, stream>>>(bufA, 256, 216, 9, wfco, b_co, Bb, 1, nullptr);
  // deformable conv -> warp (output 0)
  k_dcn_nhwc<<<1024, TPB, 0, stream>>>(xbf, Bb, wfdcn, b_dcn, warp_out);
}

// Round 22
// 446.837 us; speedup vs baseline: 1.0300x; 1.0174x over previous
//
#include <hip/hip_runtime.h>
#include <cstdint>

#define TPB 256

typedef __attribute__((ext_vector_type(8))) short s16x8;
typedef __attribute__((ext_vector_type(4))) short s16x4;
typedef __attribute__((ext_vector_type(4))) float f32x4;

__device__ __forceinline__ float silu_f(float x) { return x / (1.f + __expf(-x)); }

__device__ __forceinline__ short f2bf(float f) {
  union { float f; unsigned u; } v; v.f = f;
  unsigned r = v.u + 0x7fffu + ((v.u >> 16) & 1u);
  return (short)(r >> 16);
}
__device__ __forceinline__ float bf2f(short s) {
  union { unsigned u; float f; } v;
  v.u = ((unsigned)(unsigned short)s) << 16;
  return v.f;
}

// All conv weights -> MFMA A-fragment order (bf16), one kernel.  (math verified R3)
__global__ void k_prep_all(const float* __restrict__ w1, const float* __restrict__ w3,
                           const float* __restrict__ w4, const float* __restrict__ wco,
                           const float* __restrict__ wdcn, short* __restrict__ dst) {
  int idx = blockIdx.x * TPB + threadIdx.x;
  if (idx >= 1966080) return;
  const float* w; int Cout, Cin, taps, mode; int local = idx;
  if (idx < 131072)       { w = w1;   Cout = 256; Cin = 512; taps = 1; mode = 0; }
  else if (idx < 196608)  { w = w3;   local -= 131072;  Cout = 256; Cin = 256; taps = 1; mode = 0; }
  else if (idx < 786432)  { w = w4;   local -= 196608;  Cout = 256; Cin = 256; taps = 9; mode = 0; }
  else if (idx < 1376256) { w = wco;  local -= 786432;  Cout = 216; Cin = 256; taps = 9; mode = 0; }
  else                    { w = wdcn; local -= 1376256; Cout = 256; Cin = 256; taps = 9; mode = 1; }
  int j = local & 7;
  int l = (local >> 3) & 63;
  int ot = (local >> 9) & 15;
  int q = local >> 13;
  int tap, cb;
  if (mode == 0) { int ncb = Cin >> 5; tap = q / ncb; cb = q - tap * ncb; }
  else           { tap = q % 9; cb = q / 9; }
  int o = ot * 16 + (l & 15);
  int c = cb * 32 + ((l >> 4) & 3) * 8 + j;
  float v = 0.f;
  if (o < Cout && c < Cin) v = w[((size_t)o * Cin + c) * taps + tap];
  dst[idx] = f2bf(v);
}

// bilinear 16x16 -> 64x64 (half-pixel, edge clamp), write NHWC-512 channels 0..255
__global__ void k_upsample_nhwc(const float* __restrict__ in, short* __restrict__ outA) {
  int idx = blockIdx.x * TPB + threadIdx.x;
  if (idx >= 8 * 4096 * 256) return;
  int c = idx & 255;
  int p = idx >> 8;          // (b*4096 + y*64 + x)
  int b = p >> 12;
  int rem = p & 4095;
  int y = rem >> 6, x = rem & 63;
  float sy = (y + 0.5f) * 0.25f - 0.5f;
  float sx = (x + 0.5f) * 0.25f - 0.5f;
  float y0f = floorf(sy), x0f = floorf(sx);
  float ly = sy - y0f, lx = sx - x0f;
  int y0 = (int)y0f, x0 = (int)x0f;
  int y0c = min(15, max(0, y0)), y1c = min(15, max(0, y0 + 1));
  int x0c = min(15, max(0, x0)), x1c = min(15, max(0, x0 + 1));
  const float* src = in + (size_t)(b * 256 + c) * 256;
  float v00 = src[y0c * 16 + x0c], v01 = src[y0c * 16 + x1c];
  float v10 = src[y1c * 16 + x0c], v11 = src[y1c * 16 + x1c];
  float r = (1.f - ly) * ((1.f - lx) * v00 + lx * v01)
          + ly * ((1.f - lx) * v10 + lx * v11);
  outA[(size_t)p * 512 + c] = f2bf(r);
}

// main f32 NCHW -> bf16 NHWC-256 (xbf) + NHWC-512 ch 256..511 (conv1 input).
__global__ __launch_bounds__(256) void k_main_tr(const float* __restrict__ in,
    short* __restrict__ xbf, short* __restrict__ outA) {
  const int pc = blockIdx.x, ck = blockIdx.y, b = blockIdx.z;
  __shared__ float sl[32][66];
  const int t = threadIdx.x;
  const int pxl = t & 63, cs = t >> 6;
  const float* src = in + (size_t)(b * 256 + ck * 32) * 4096 + pc * 64;
  #pragma unroll
  for (int i = 0; i < 8; ++i) {
    int c = i * 4 + cs;
    sl[c][pxl] = src[(size_t)c * 4096 + pxl];
  }
  __syncthreads();
  const int oct = (t & 3) * 8, px2 = t >> 2;
  s16x8 v;
  #pragma unroll
  for (int j = 0; j < 8; ++j) v[j] = f2bf(sl[oct + j][px2]);
  size_t p = (size_t)b * 4096 + pc * 64 + px2;
  *(s16x8*)(xbf + p * 256 + ck * 32 + oct) = v;
  *(s16x8*)(outA + p * 512 + 256 + ck * 32 + oct) = v;
}

// NHWC MFMA conv, 2-row blocks, XCD-swizzled 1D grid (b = gid&7).
__global__ __launch_bounds__(256) void k_conv2(
    const short* __restrict__ in, int Cin, int Cout, int taps,
    const short* __restrict__ wf, const float* __restrict__ bias,
    short* __restrict__ out, int remap) {
  const int gid = blockIdx.x;
  const int b = gid & 7;
  const int r = gid >> 3;
  const int og = r & 3, yt = r >> 2;
  const int t = threadIdx.x;
  const int wid = t >> 6, l = t & 63;
  const int wo = wid >> 1, wr = wid & 1;
  const int pd = (taps == 9) ? 1 : 0;
  const int rows_in = 2 + 2 * pd;              // 2 or 4
  const int pxw = 64 + 2 * pd;                 // 64 or 66
  const int ncb = Cin >> 5;
  const int nchunk = Cin >> 6;
  const int ndy = (taps == 9) ? 3 : 1;
  __shared__ __align__(16) short sl[4 * 66 * 68];
  f32x4 acc[2][4];
  #pragma unroll
  for (int i = 0; i < 2; ++i)
    #pragma unroll
    for (int j = 0; j < 4; ++j) acc[i][j] = (f32x4){0.f, 0.f, 0.f, 0.f};
  const int y0g = yt * 2 - pd;                 // global row of LDS row 0
  for (int chunk = 0; chunk < nchunk; ++chunk) {
    __syncthreads();
    {
      const int nun = rows_in * pxw * 8;       // s16x8 units (max 2112)
      const int c0 = chunk * 64;
      #pragma unroll
      for (int i = 0; i < 9; ++i) {
        int e = t + i * 256;
        if (e < nun) {
          int oct = e & 7;
          int pe = e >> 3;
          int pxs = pe % pxw;
          int row = pe / pxw;
          int yy = y0g + row, xx = pxs - pd;
          s16x8 v = {0, 0, 0, 0, 0, 0, 0, 0};
          if (yy >= 0 && yy < 64 && xx >= 0 && xx < 64)
            v = *(const s16x8*)(in + (size_t)((b * 64 + yy) * 64 + xx) * Cin
                                + c0 + oct * 8);
          *(s16x8*)(sl + (row * 66 + pxs) * 68 + oct * 8) = v;
        }
      }
    }
    __syncthreads();
    #pragma unroll 2
    for (int cb = 0; cb < 2; ++cb) {
      const int qc = chunk * 2 + cb;
      for (int dyi = 0; dyi < ndy; ++dyi) {
        const int lrow = wr + dyi;            // LDS row (wr+dy+pd)
        for (int dxi = 0; dxi < ndy; ++dxi) {
          const int tap = (taps == 9) ? dyi * 3 + dxi : 0;
          const int q = tap * ncb + qc;
          s16x8 afr[2];
          #pragma unroll
          for (int i = 0; i < 2; ++i) {
            int ot = og * 4 + wo * 2 + i;
            afr[i] = *(const s16x8*)(wf + (((size_t)q * 16 + ot) * 64 + l) * 8);
          }
          #pragma unroll
          for (int jt = 0; jt < 4; ++jt) {
            int pxi = jt * 16 + (l & 15) + dxi;   // dx+pd = dxi
            s16x8 bfr = *(const s16x8*)(sl + (lrow * 66 + pxi) * 68
                                        + cb * 32 + (l >> 4) * 8);
            #pragma unroll
            for (int i = 0; i < 2; ++i)
              acc[i][jt] = __builtin_amdgcn_mfma_f32_16x16x32_bf16(
                  afr[i], bfr, acc[i][jt], 0, 0, 0);
          }
        }
      }
    }
  }
  const int y = yt * 2 + wr;
  #pragma unroll
  for (int i = 0; i < 2; ++i) {
    #pragma unroll
    for (int jt = 0; jt < 4; ++jt) {
      int px = jt * 16 + (l & 15);
      int obase = og * 64 + wo * 32 + i * 16 + (l >> 4) * 4;
      size_t pbase = (size_t)((b * 64 + y) * 64 + px) * (remap ? 256 : Cout);
      if (!remap) {
        s16x4 r2;
        #pragma unroll
        for (int rr = 0; rr < 4; ++rr) r2[rr] = f2bf(acc[i][jt][rr] + bias[obase + rr]);
        *(s16x4*)(out + pbase + obase) = r2;
      } else {
        #pragma unroll
        for (int rr = 0; rr < 4; ++rr) {
          int o = obase + rr;
          if (o < Cout) {
            int op;
            if (o < 144) op = (o / 18) * 32 + (o % 18);
            else { int jj = o - 144; op = (jj / 9) * 32 + 18 + (jj % 9); }
            out[pbase + op] = f2bf(acc[i][jt][rr] + bias[o]);
          }
        }
      }
    }
  }
}

// GroupNorm stats pass: 2048 1D blocks, XCD-swizzled: b = gid&7, r=gid>>3,
// ck = r&7 (512-px chunk), g = r>>3. Partial sums -> parts[gid*2 + {0,1}].
__global__ __launch_bounds__(256) void k_gn_stats(const short* __restrict__ io,
    float* __restrict__ parts) {
  const int gid = blockIdx.x;
  const int b = gid & 7;
  const int r = gid >> 3;
  const int ck = r & 7, g = r >> 3;
  const int t = threadIdx.x;
  float s = 0.f, sq = 0.f;
  #pragma unroll
  for (int i = 0; i < 2; ++i) {
    int e = ck * 512 + t + i * 256;
    s16x8 v = *(const s16x8*)(io + (size_t)(b * 4096 + e) * 256 + g * 8);
    #pragma unroll
    for (int j = 0; j < 8; ++j) { float f = bf2f(v[j]); s += f; sq += f * f; }
  }
  #pragma unroll
  for (int off = 32; off > 0; off >>= 1) {
    s += __shfl_down(s, off);
    sq += __shfl_down(sq, off);
  }
  __shared__ float ps[4], pq[4];
  const int wv = t >> 6, lane = t & 63;
  if (lane == 0) { ps[wv] = s; pq[wv] = sq; }
  __syncthreads();
  if (t == 0) {
    parts[gid * 2]     = ps[0] + ps[1] + ps[2] + ps[3];
    parts[gid * 2 + 1] = pq[0] + pq[1] + pq[2] + pq[3];
  }
}

// GroupNorm apply + SiLU: reduces the 8 chunk-partials of (b,g), applies to
// its 512 px x 8 ch slice in-place (bf16) + optional f32 NCHW out.
__global__ __launch_bounds__(256) void k_gn_apply(short* __restrict__ io,
    float* __restrict__ f32out, const float* __restrict__ parts,
    const float* __restrict__ gamma, const float* __restrict__ beta) {
  const int gid = blockIdx.x;
  const int b = gid & 7;
  const int r = gid >> 3;
  const int ck = r & 7, g = r >> 3;
  const int t = threadIdx.x;
  float S = 0.f, Q = 0.f;
  #pragma unroll
  for (int i = 0; i < 8; ++i) {
    int gid2 = (((g << 3) | i) << 3) | b;
    S += parts[gid2 * 2];
    Q += parts[gid2 * 2 + 1];
  }
  const float mean = S * (1.f / 32768.f);
  const float var = Q * (1.f / 32768.f) - mean * mean;
  const float rs = rsqrtf(var + 1e-6f);
  float ga[8], bb[8];
  #pragma unroll
  for (int j = 0; j < 8; ++j) {
    ga[j] = gamma[g * 8 + j] * rs;
    bb[j] = beta[g * 8 + j] - mean * ga[j];
  }
  #pragma unroll
  for (int i = 0; i < 2; ++i) {
    int e = ck * 512 + t + i * 256;
    short* ptr = io + (size_t)(b * 4096 + e) * 256 + g * 8;
    s16x8 v = *(const s16x8*)ptr;
    s16x8 r2;
    #pragma unroll
    for (int j = 0; j < 8; ++j) {
      float o = silu_f(bf2f(v[j]) * ga[j] + bb[j]);
      r2[j] = f2bf(o);
      if (f32out) f32out[(size_t)(b * 256 + g * 8 + j) * 4096 + e] = o;
    }
    *(s16x8*)ptr = r2;
  }
}

// depthwise 7x7 pad 3, NHWC bf16, LDS-staged, XCD-swizzled 1D grid.
__global__ __launch_bounds__(256) void k_dw7_nhwc(const short* __restrict__ in,
    const float* __restrict__ w, const float* __restrict__ bias,
    short* __restrict__ out) {
  const int gid = blockIdx.x;
  const int b = gid & 7;
  const int r = gid >> 3;
  const int ck = r & 7, yt = r >> 3;
  const int t = threadIdx.x;
  const int px = t & 63, oc = t >> 6;
  __shared__ __align__(16) short sl[10 * 70 * 40];
  __shared__ float wl[49 * 32];
  for (int e = t; e < 49 * 32; e += TPB) {
    int tap = e >> 5, cc = e & 31;
    wl[tap * 32 + cc] = w[(ck * 32 + cc) * 49 + tap];
  }
  const int y0in = yt * 4 - 3;
  #pragma unroll
  for (int i = 0; i < 11; ++i) {
    int e = t + i * TPB;
    if (e < 2800) {
      int oc2 = e & 3;
      int pe = e >> 2;
      int pxs = pe % 70;
      int row = pe / 70;
      int yy = y0in + row, xx = pxs - 3;
      s16x8 v = {0, 0, 0, 0, 0, 0, 0, 0};
      if (yy >= 0 && yy < 64 && xx >= 0 && xx < 64)
        v = *(const s16x8*)(in + (size_t)((b * 64 + yy) * 64 + xx) * 256
                            + ck * 32 + oc2 * 8);
      *(s16x8*)(sl + (row * 70 + pxs) * 40 + oc2 * 8) = v;
    }
  }
  __syncthreads();
  float acc[4][8];
  {
    float4 b0 = *(const float4*)(bias + ck * 32 + oc * 8);
    float4 b1 = *(const float4*)(bias + ck * 32 + oc * 8 + 4);
    #pragma unroll
    for (int r2 = 0; r2 < 4; ++r2) {
      acc[r2][0] = b0.x; acc[r2][1] = b0.y; acc[r2][2] = b0.z; acc[r2][3] = b0.w;
      acc[r2][4] = b1.x; acc[r2][5] = b1.y; acc[r2][6] = b1.z; acc[r2][7] = b1.w;
    }
  }
  #pragma unroll
  for (int ky = 0; ky < 7; ++ky) {
    #pragma unroll
    for (int kx = 0; kx < 7; ++kx) {
      const float4 w0 = *(const float4*)(wl + (ky * 7 + kx) * 32 + oc * 8);
      const float4 w1 = *(const float4*)(wl + (ky * 7 + kx) * 32 + oc * 8 + 4);
      #pragma unroll
      for (int r2 = 0; r2 < 4; ++r2) {
        s16x8 v = *(const s16x8*)(sl + ((r2 + ky) * 70 + (px + kx)) * 40 + oc * 8);
        acc[r2][0] += bf2f(v[0]) * w0.x; acc[r2][1] += bf2f(v[1]) * w0.y;
        acc[r2][2] += bf2f(v[2]) * w0.z; acc[r2][3] += bf2f(v[3]) * w0.w;
        acc[r2][4] += bf2f(v[4]) * w1.x; acc[r2][5] += bf2f(v[5]) * w1.y;
        acc[r2][6] += bf2f(v[6]) * w1.z; acc[r2][7] += bf2f(v[7]) * w1.w;
      }
    }
  }
  #pragma unroll
  for (int r2 = 0; r2 < 4; ++r2) {
    int y = yt * 4 + r2;
    s16x8 o;
    #pragma unroll
    for (int j = 0; j < 8; ++j) o[j] = f2bf(acc[r2][j]);
    *(s16x8*)(out + (size_t)((b * 64 + y) * 64 + px) * 256 + ck * 32 + oc * 8) = o;
  }
}

// Deformable conv v2 via MFMA, NHWC, px-split, XCD-swizzled (b = gid&7).
// Phase A: per-(px,k) bilinear weights/addresses once -> LDS table (9-stride).
// Phase B: gather+blend. Phase C: MFMA. (R19 verified, 134us.)
__global__ __launch_bounds__(256) void k_dcn_nhwc(const short* __restrict__ x,
    const short* __restrict__ co, const short* __restrict__ wf,
    const float* __restrict__ bias, float* __restrict__ out) {
  const int gid = blockIdx.x;
  const int b = gid & 7;
  const int r = gid >> 3;
  const int ph = r & 1, y = r >> 1;
  const int t = threadIdx.x;
  const int wid = t >> 6, l = t & 63;
  const int px0 = ph * 32;
  __shared__ __align__(16) short s2[9 * 32 * 40];
  __shared__ unsigned swt[288 * 9];   // [k*32+pxl]: w00..w11 (f32 bits), i00..i11
  f32x4 acc[4][2];
  #pragma unroll
  for (int i = 0; i < 4; ++i)
    #pragma unroll
    for (int j = 0; j < 2; ++j) acc[i][j] = (f32x4){0.f, 0.f, 0.f, 0.f};
  const short* xb = x + (size_t)b * 4096 * 256;
  for (int g = 0; g < 8; ++g) {
    __syncthreads();
    // phase A: 288 dense weight/address tasks (pxl, k)
    #pragma unroll
    for (int i = 0; i < 2; ++i) {
      int e2 = t + i * 256;
      if (e2 < 288) {
        int pxl = e2 & 31, k = e2 >> 5;
        int px = px0 + pxl;
        const short* cp = co + (size_t)(b * 4096 + y * 64 + px) * 256 + g * 32;
        float offy = bf2f(cp[2 * k]);
        float offx = bf2f(cp[2 * k + 1]);
        float mlog = bf2f(cp[18 + k]);
        float mv = 1.f / (1.f + __expf(-mlog));
        float py = offy + (float)(y - 1 + k / 3);
        float pxf = offx + (float)(px - 1 + k % 3);
        float y0f = floorf(py), x0f = floorf(pxf);
        float ly = py - y0f, lx = pxf - x0f;
        int y0 = (int)y0f, x0 = (int)x0f;
        int y1 = y0 + 1, x1 = x0 + 1;
        float fy0 = (y0 >= 0 && y0 < 64) ? 1.f : 0.f;
        float fy1 = (y1 >= 0 && y1 < 64) ? 1.f : 0.f;
        float fx0 = (x0 >= 0 && x0 < 64) ? 1.f : 0.f;
        float fx1 = (x1 >= 0 && x1 < 64) ? 1.f : 0.f;
        float w00 = (1.f - ly) * (1.f - lx) * fy0 * fx0 * mv;
        float w01 = (1.f - ly) * lx * fy0 * fx1 * mv;
        float w10 = ly * (1.f - lx) * fy1 * fx0 * mv;
        float w11 = ly * lx * fy1 * fx1 * mv;
        int y0c = min(63, max(0, y0)), y1c = min(63, max(0, y1));
        int x0c = min(63, max(0, x0)), x1c = min(63, max(0, x1));
        unsigned* wp = swt + e2 * 9;
        wp[0] = __float_as_uint(w00);
        wp[1] = __float_as_uint(w01);
        wp[2] = __float_as_uint(w10);
        wp[3] = __float_as_uint(w11);
        wp[4] = (unsigned)((y0c * 64 + x0c) * 256);
        wp[5] = (unsigned)((y0c * 64 + x1c) * 256);
        wp[6] = (unsigned)((y1c * 64 + x0c) * 256);
        wp[7] = (unsigned)((y1c * 64 + x1c) * 256);
      }
    }
    __syncthreads();
    // phase B: 1152 sampling tasks = 4 oct x 32 px x 9 k (gather + blend)
    #pragma unroll
    for (int i = 0; i < 5; ++i) {
      int e = t + i * 256;
      if (e < 1152) {
        int oct = e & 3, pxl = (e >> 2) & 31, k = e >> 7;
        const unsigned* wp = swt + (k * 32 + pxl) * 9;
        float w00 = __uint_as_float(wp[0]);
        float w01 = __uint_as_float(wp[1]);
        float w10 = __uint_as_float(wp[2]);
        float w11 = __uint_as_float(wp[3]);
        const short* xc = xb + g * 32 + oct * 8;
        s16x8 c00 = *(const s16x8*)(xc + wp[4]);
        s16x8 c01 = *(const s16x8*)(xc + wp[5]);
        s16x8 c10 = *(const s16x8*)(xc + wp[6]);
        s16x8 c11 = *(const s16x8*)(xc + wp[7]);
        s16x8 pk;
        #pragma unroll
        for (int cc = 0; cc < 8; ++cc) {
          float v = w00 * bf2f(c00[cc]) + w01 * bf2f(c01[cc])
                  + w10 * bf2f(c10[cc]) + w11 * bf2f(c11[cc]);
          pk[cc] = f2bf(v);
        }
        *(s16x8*)(s2 + (k * 32 + pxl) * 40 + oct * 8) = pk;
      }
    }
    __syncthreads();
    // phase C: MFMA (unchanged)
    #pragma unroll
    for (int k = 0; k < 9; ++k) {
      const int q = g * 9 + k;
      s16x8 afr[4], bfr[2];
      #pragma unroll
      for (int i = 0; i < 4; ++i)
        afr[i] = *(const s16x8*)(wf + (((size_t)q * 16 + wid * 4 + i) * 64 + l) * 8);
      #pragma unroll
      for (int jt = 0; jt < 2; ++jt)
        bfr[jt] = *(const s16x8*)(s2 + (k * 32 + jt * 16 + (l & 15)) * 40 + (l >> 4) * 8);
      #pragma unroll
      for (int i = 0; i < 4; ++i)
        #pragma unroll
        for (int jt = 0; jt < 2; ++jt)
          acc[i][jt] = __builtin_amdgcn_mfma_f32_16x16x32_bf16(
              afr[i], bfr[jt], acc[i][jt], 0, 0, 0);
    }
  }
  #pragma unroll
  for (int i = 0; i < 4; ++i) {
    int obase = wid * 64 + i * 16 + (l >> 4) * 4;
    #pragma unroll
    for (int jt = 0; jt < 2; ++jt) {
      int pxo = px0 + jt * 16 + (l & 15);
      #pragma unroll
      for (int rr = 0; rr < 4; ++rr) {
        int o = obase + rr;
        out[(((size_t)b * 256 + o) * 64 + y) * 64 + pxo] = acc[i][jt][rr] + bias[o];
      }
    }
  }
}

extern "C" void kernel_launch(void* const* d_in, const int* in_sizes, int n_in,
                              void* d_out, int out_size, void* d_ws, size_t ws_size,
                              hipStream_t stream) {
  const float* main_f = (const float*)d_in[0];
  const float* cond   = (const float*)d_in[1];
  const float* w1  = (const float*)d_in[2];
  const float* b1  = (const float*)d_in[3];
  const float* g1  = (const float*)d_in[4];
  const float* be1 = (const float*)d_in[5];
  const float* w2  = (const float*)d_in[6];
  const float* b2  = (const float*)d_in[7];
  const float* g2  = (const float*)d_in[8];
  const float* be2 = (const float*)d_in[9];
  const float* w3  = (const float*)d_in[10];
  const float* b3  = (const float*)d_in[11];
  const float* w4  = (const float*)d_in[12];
  const float* b4  = (const float*)d_in[13];
  const float* g3  = (const float*)d_in[14];
  const float* be3 = (const float*)d_in[15];
  const float* w_co  = (const float*)d_in[16];
  const float* b_co  = (const float*)d_in[17];
  const float* w_dcn = (const float*)d_in[18];
  const float* b_dcn = (const float*)d_in[19];

  float* out = (float*)d_out;
  float* warp_out = out;               // [8,256,64,64] f32 NCHW
  float* offset_feat = out + 8388608;  // [8,256,64,64] f32 NCHW

  short* ws = (short*)d_ws;
  short* bufA  = ws;                   // NHWC-512 conv1 input: 16777216
  short* Bb    = bufA + 16777216;      // NHWC-256: 8388608
  short* xbf   = Bb + 8388608;         // main NHWC-256 bf16: 8388608
  short* wfall = xbf + 8388608;        // contiguous: wf1 wf3 wf4 wfco wfdcn
  short* wf1   = wfall;                // 131072
  short* wf3   = wf1 + 131072;         // 65536
  short* wf4   = wf3 + 65536;          // 589824
  short* wfco  = wf4 + 589824;         // 589824
  short* wfdcn = wfco + 589824;        // 589824
  float* gparts = (float*)(wfdcn + 589824);  // 2048*2 f32

  auto cdiv = [](int a, int b) { return (a + b - 1) / b; };

  k_prep_all<<<cdiv(1966080, TPB), TPB, 0, stream>>>(w1, w3, w4, w_co, w_dcn, wfall);

  k_upsample_nhwc<<<cdiv(8 * 4096 * 256, TPB), TPB, 0, stream>>>(cond, bufA);
  dim3 gtr(64, 8, 8);
  k_main_tr<<<gtr, TPB, 0, stream>>>(main_f, xbf, bufA);

  // conv grids: 1D 1024 blocks, XCD-swizzled (b = gid&7)
  k_conv2<<<1024, TPB, 0, stream>>>(bufA, 512, 256, 1, wf1, b1, Bb, 0);
  k_gn_stats<<<2048, TPB, 0, stream>>>(Bb, gparts);
  k_gn_apply<<<2048, TPB, 0, stream>>>(Bb, nullptr, gparts, g1, be1);
  k_dw7_nhwc<<<1024, TPB, 0, stream>>>(Bb, w2, b2, bufA);
  k_gn_stats<<<2048, TPB, 0, stream>>>(bufA, gparts);
  k_gn_apply<<<2048, TPB, 0, stream>>>(bufA, nullptr, gparts, g2, be2);
  k_conv2<<<1024, TPB, 0, stream>>>(bufA, 256, 256, 1, wf3, b3, Bb, 0);
  k_conv2<<<1024, TPB, 0, stream>>>(Bb, 256, 256, 9, wf4, b4, bufA, 0);
  k_gn_stats<<<2048, TPB, 0, stream>>>(bufA, gparts);
  k_gn_apply<<<2048, TPB, 0, stream>>>(bufA, offset_feat, gparts, g3, be3);
  k_conv2<<<1024, TPB, 0, stream>>>(bufA, 256, 216, 9, wfco, b_co, Bb, 1);
  // deformable conv -> warp (output 0)
  k_dcn_nhwc<<<1024, TPB, 0, stream>>>(xbf, Bb, wfdcn, b_dcn, warp_out);
}

// Round 23
// 439.113 us; speedup vs baseline: 1.0481x; 1.0176x over previous
//
#include <hip/hip_runtime.h>
#include <cstdint>

#define TPB 256

typedef __attribute__((ext_vector_type(8))) short s16x8;
typedef __attribute__((ext_vector_type(4))) short s16x4;
typedef __attribute__((ext_vector_type(4))) float f32x4;

__device__ __forceinline__ float silu_f(float x) { return x / (1.f + __expf(-x)); }

__device__ __forceinline__ short f2bf(float f) {
  union { float f; unsigned u; } v; v.f = f;
  unsigned r = v.u + 0x7fffu + ((v.u >> 16) & 1u);
  return (short)(r >> 16);
}
__device__ __forceinline__ float bf2f(short s) {
  union { unsigned u; float f; } v;
  v.u = ((unsigned)(unsigned short)s) << 16;
  return v.f;
}

// All conv weights -> MFMA A-fragment order (bf16), one kernel.  (math verified R3)
__global__ void k_prep_all(const float* __restrict__ w1, const float* __restrict__ w3,
                           const float* __restrict__ w4, const float* __restrict__ wco,
                           const float* __restrict__ wdcn, short* __restrict__ dst) {
  int idx = blockIdx.x * TPB + threadIdx.x;
  if (idx >= 1966080) return;
  const float* w; int Cout, Cin, taps, mode; int local = idx;
  if (idx < 131072)       { w = w1;   Cout = 256; Cin = 512; taps = 1; mode = 0; }
  else if (idx < 196608)  { w = w3;   local -= 131072;  Cout = 256; Cin = 256; taps = 1; mode = 0; }
  else if (idx < 786432)  { w = w4;   local -= 196608;  Cout = 256; Cin = 256; taps = 9; mode = 0; }
  else if (idx < 1376256) { w = wco;  local -= 786432;  Cout = 216; Cin = 256; taps = 9; mode = 0; }
  else                    { w = wdcn; local -= 1376256; Cout = 256; Cin = 256; taps = 9; mode = 1; }
  int j = local & 7;
  int l = (local >> 3) & 63;
  int ot = (local >> 9) & 15;
  int q = local >> 13;
  int tap, cb;
  if (mode == 0) { int ncb = Cin >> 5; tap = q / ncb; cb = q - tap * ncb; }
  else           { tap = q % 9; cb = q / 9; }
  int o = ot * 16 + (l & 15);
  int c = cb * 32 + ((l >> 4) & 3) * 8 + j;
  float v = 0.f;
  if (o < Cout && c < Cin) v = w[((size_t)o * Cin + c) * taps + tap];
  dst[idx] = f2bf(v);
}

// bilinear 16x16 -> 64x64 (half-pixel, edge clamp), write NHWC-512 channels 0..255
__global__ void k_upsample_nhwc(const float* __restrict__ in, short* __restrict__ outA) {
  int idx = blockIdx.x * TPB + threadIdx.x;
  if (idx >= 8 * 4096 * 256) return;
  int c = idx & 255;
  int p = idx >> 8;          // (b*4096 + y*64 + x)
  int b = p >> 12;
  int rem = p & 4095;
  int y = rem >> 6, x = rem & 63;
  float sy = (y + 0.5f) * 0.25f - 0.5f;
  float sx = (x + 0.5f) * 0.25f - 0.5f;
  float y0f = floorf(sy), x0f = floorf(sx);
  float ly = sy - y0f, lx = sx - x0f;
  int y0 = (int)y0f, x0 = (int)x0f;
  int y0c = min(15, max(0, y0)), y1c = min(15, max(0, y0 + 1));
  int x0c = min(15, max(0, x0)), x1c = min(15, max(0, x0 + 1));
  const float* src = in + (size_t)(b * 256 + c) * 256;
  float v00 = src[y0c * 16 + x0c], v01 = src[y0c * 16 + x1c];
  float v10 = src[y1c * 16 + x0c], v11 = src[y1c * 16 + x1c];
  float r = (1.f - ly) * ((1.f - lx) * v00 + lx * v01)
          + ly * ((1.f - lx) * v10 + lx * v11);
  outA[(size_t)p * 512 + c] = f2bf(r);
}

// main f32 NCHW -> bf16 NHWC-256 (xbf) + NHWC-512 ch 256..511 (conv1 input).
__global__ __launch_bounds__(256) void k_main_tr(const float* __restrict__ in,
    short* __restrict__ xbf, short* __restrict__ outA) {
  const int pc = blockIdx.x, ck = blockIdx.y, b = blockIdx.z;
  __shared__ float sl[32][66];
  const int t = threadIdx.x;
  const int pxl = t & 63, cs = t >> 6;
  const float* src = in + (size_t)(b * 256 + ck * 32) * 4096 + pc * 64;
  #pragma unroll
  for (int i = 0; i < 8; ++i) {
    int c = i * 4 + cs;
    sl[c][pxl] = src[(size_t)c * 4096 + pxl];
  }
  __syncthreads();
  const int oct = (t & 3) * 8, px2 = t >> 2;
  s16x8 v;
  #pragma unroll
  for (int j = 0; j < 8; ++j) v[j] = f2bf(sl[oct + j][px2]);
  size_t p = (size_t)b * 4096 + pc * 64 + px2;
  *(s16x8*)(xbf + p * 256 + ck * 32 + oct) = v;
  *(s16x8*)(outA + p * 512 + 256 + ck * 32 + oct) = v;
}

// NHWC MFMA conv, 2-row blocks, XCD-swizzled 1D grid (b = gid&7).
// stats != nullptr (non-remap only): epilogue accumulates per-(b,group,yt)
// {sum, sumsq} of the STORED bf16 output into stats[((b*32+gg)<<5)+yt]
// via deterministic shfl_xor butterfly + LDS combine (1x redundancy).
__global__ __launch_bounds__(256) void k_conv2(
    const short* __restrict__ in, int Cin, int Cout, int taps,
    const short* __restrict__ wf, const float* __restrict__ bias,
    short* __restrict__ out, int remap, float2* __restrict__ stats) {
  const int gid = blockIdx.x;
  const int b = gid & 7;
  const int r = gid >> 3;
  const int og = r & 3, yt = r >> 2;
  const int t = threadIdx.x;
  const int wid = t >> 6, l = t & 63;
  const int wo = wid >> 1, wr = wid & 1;
  const int pd = (taps == 9) ? 1 : 0;
  const int rows_in = 2 + 2 * pd;              // 2 or 4
  const int pxw = 64 + 2 * pd;                 // 64 or 66
  const int ncb = Cin >> 5;
  const int nchunk = Cin >> 6;
  const int ndy = (taps == 9) ? 3 : 1;
  __shared__ __align__(16) short sl[4 * 66 * 68];
  __shared__ float sred[2][8][2];
  f32x4 acc[2][4];
  #pragma unroll
  for (int i = 0; i < 2; ++i)
    #pragma unroll
    for (int j = 0; j < 4; ++j) acc[i][j] = (f32x4){0.f, 0.f, 0.f, 0.f};
  const int y0g = yt * 2 - pd;                 // global row of LDS row 0
  for (int chunk = 0; chunk < nchunk; ++chunk) {
    __syncthreads();
    {
      const int nun = rows_in * pxw * 8;       // s16x8 units (max 2112)
      const int c0 = chunk * 64;
      #pragma unroll
      for (int i = 0; i < 9; ++i) {
        int e = t + i * 256;
        if (e < nun) {
          int oct = e & 7;
          int pe = e >> 3;
          int pxs = pe % pxw;
          int row = pe / pxw;
          int yy = y0g + row, xx = pxs - pd;
          s16x8 v = {0, 0, 0, 0, 0, 0, 0, 0};
          if (yy >= 0 && yy < 64 && xx >= 0 && xx < 64)
            v = *(const s16x8*)(in + (size_t)((b * 64 + yy) * 64 + xx) * Cin
                                + c0 + oct * 8);
          *(s16x8*)(sl + (row * 66 + pxs) * 68 + oct * 8) = v;
        }
      }
    }
    __syncthreads();
    #pragma unroll 2
    for (int cb = 0; cb < 2; ++cb) {
      const int qc = chunk * 2 + cb;
      for (int dyi = 0; dyi < ndy; ++dyi) {
        const int lrow = wr + dyi;            // LDS row (wr+dy+pd)
        for (int dxi = 0; dxi < ndy; ++dxi) {
          const int tap = (taps == 9) ? dyi * 3 + dxi : 0;
          const int q = tap * ncb + qc;
          s16x8 afr[2];
          #pragma unroll
          for (int i = 0; i < 2; ++i) {
            int ot = og * 4 + wo * 2 + i;
            afr[i] = *(const s16x8*)(wf + (((size_t)q * 16 + ot) * 64 + l) * 8);
          }
          #pragma unroll
          for (int jt = 0; jt < 4; ++jt) {
            int pxi = jt * 16 + (l & 15) + dxi;   // dx+pd = dxi
            s16x8 bfr = *(const s16x8*)(sl + (lrow * 66 + pxi) * 68
                                        + cb * 32 + (l >> 4) * 8);
            #pragma unroll
            for (int i = 0; i < 2; ++i)
              acc[i][jt] = __builtin_amdgcn_mfma_f32_16x16x32_bf16(
                  afr[i], bfr, acc[i][jt], 0, 0, 0);
          }
        }
      }
    }
  }
  const int y = yt * 2 + wr;
  float ss[2] = {0.f, 0.f}, qq[2] = {0.f, 0.f};
  #pragma unroll
  for (int i = 0; i < 2; ++i) {
    #pragma unroll
    for (int jt = 0; jt < 4; ++jt) {
      int px = jt * 16 + (l & 15);
      int obase = og * 64 + wo * 32 + i * 16 + (l >> 4) * 4;
      size_t pbase = (size_t)((b * 64 + y) * 64 + px) * (remap ? 256 : Cout);
      if (!remap) {
        s16x4 r2;
        #pragma unroll
        for (int rr = 0; rr < 4; ++rr) {
          r2[rr] = f2bf(acc[i][jt][rr] + bias[obase + rr]);
          if (stats) { float v = bf2f(r2[rr]); ss[i] += v; qq[i] += v * v; }
        }
        *(s16x4*)(out + pbase + obase) = r2;
      } else {
        #pragma unroll
        for (int rr = 0; rr < 4; ++rr) {
          int o = obase + rr;
          if (o < Cout) {
            int op;
            if (o < 144) op = (o / 18) * 32 + (o % 18);
            else { int jj = o - 144; op = (jj / 9) * 32 + 18 + (jj % 9); }
            out[pbase + op] = f2bf(acc[i][jt][rr] + bias[o]);
          }
        }
      }
    }
  }
  if (stats && !remap) {
    // butterfly within each 32-lane half (lanes 0-31: ch-sub 0-7; 32-63: 8-15)
    #pragma unroll
    for (int i = 0; i < 2; ++i) {
      float s = ss[i], q = qq[i];
      #pragma unroll
      for (int m = 1; m <= 16; m <<= 1) {
        s += __shfl_xor(s, m);
        q += __shfl_xor(q, m);
      }
      if ((l & 31) == 0) {
        int gl = wo * 4 + i * 2 + (l >> 5);   // local group 0..7
        sred[wr][gl][0] = (wr == 0) ? s : s;  // distinct [wr] slots
        sred[wr][gl][1] = q;
        sred[wr][gl][0] = s;
      }
    }
    __syncthreads();
    if (t < 8) {
      float S = sred[0][t][0] + sred[1][t][0];
      float Q = sred[0][t][1] + sred[1][t][1];
      stats[(((size_t)b * 32 + og * 8 + t) << 5) + yt] = make_float2(S, Q);
    }
  }
}

// GroupNorm apply + SiLU: reduces np yt-partials of (b,g) in fixed order,
// applies to its 512 px x 8 ch slice in-place (bf16) + optional f32 NCHW out.
__global__ __launch_bounds__(256) void k_gn_apply(short* __restrict__ io,
    float* __restrict__ f32out, const float2* __restrict__ parts, int np,
    const float* __restrict__ gamma, const float* __restrict__ beta) {
  const int gid = blockIdx.x;
  const int b = gid & 7;
  const int r = gid >> 3;
  const int ck = r & 7, g = r >> 3;
  const int t = threadIdx.x;
  float S = 0.f, Q = 0.f;
  const float2* pp = parts + (((size_t)b * 32 + g) << 5);
  for (int i = 0; i < np; ++i) { float2 p = pp[i]; S += p.x; Q += p.y; }
  const float mean = S * (1.f / 32768.f);
  const float var = Q * (1.f / 32768.f) - mean * mean;
  const float rs = rsqrtf(var + 1e-6f);
  float ga[8], bb[8];
  #pragma unroll
  for (int j = 0; j < 8; ++j) {
    ga[j] = gamma[g * 8 + j] * rs;
    bb[j] = beta[g * 8 + j] - mean * ga[j];
  }
  #pragma unroll
  for (int i = 0; i < 2; ++i) {
    int e = ck * 512 + t + i * 256;
    short* ptr = io + (size_t)(b * 4096 + e) * 256 + g * 8;
    s16x8 v = *(const s16x8*)ptr;
    s16x8 r2;
    #pragma unroll
    for (int j = 0; j < 8; ++j) {
      float o = silu_f(bf2f(v[j]) * ga[j] + bb[j]);
      r2[j] = f2bf(o);
      if (f32out) f32out[(size_t)(b * 256 + g * 8 + j) * 4096 + e] = o;
    }
    *(s16x8*)ptr = r2;
  }
}

// depthwise 7x7 pad 3, NHWC bf16, LDS-staged, XCD-swizzled 1D grid.
// stats: per-(b,group,yt) {sum,sumsq} of stored output (wave = 1 group x 64 px).
__global__ __launch_bounds__(256) void k_dw7_nhwc(const short* __restrict__ in,
    const float* __restrict__ w, const float* __restrict__ bias,
    short* __restrict__ out, float2* __restrict__ stats) {
  const int gid = blockIdx.x;
  const int b = gid & 7;
  const int r = gid >> 3;
  const int ck = r & 7, yt = r >> 3;
  const int t = threadIdx.x;
  const int px = t & 63, oc = t >> 6;
  __shared__ __align__(16) short sl[10 * 70 * 40];
  __shared__ float wl[49 * 32];
  for (int e = t; e < 49 * 32; e += TPB) {
    int tap = e >> 5, cc = e & 31;
    wl[tap * 32 + cc] = w[(ck * 32 + cc) * 49 + tap];
  }
  const int y0in = yt * 4 - 3;
  #pragma unroll
  for (int i = 0; i < 11; ++i) {
    int e = t + i * TPB;
    if (e < 2800) {
      int oc2 = e & 3;
      int pe = e >> 2;
      int pxs = pe % 70;
      int row = pe / 70;
      int yy = y0in + row, xx = pxs - 3;
      s16x8 v = {0, 0, 0, 0, 0, 0, 0, 0};
      if (yy >= 0 && yy < 64 && xx >= 0 && xx < 64)
        v = *(const s16x8*)(in + (size_t)((b * 64 + yy) * 64 + xx) * 256
                            + ck * 32 + oc2 * 8);
      *(s16x8*)(sl + (row * 70 + pxs) * 40 + oc2 * 8) = v;
    }
  }
  __syncthreads();
  float acc[4][8];
  {
    float4 b0 = *(const float4*)(bias + ck * 32 + oc * 8);
    float4 b1 = *(const float4*)(bias + ck * 32 + oc * 8 + 4);
    #pragma unroll
    for (int r2 = 0; r2 < 4; ++r2) {
      acc[r2][0] = b0.x; acc[r2][1] = b0.y; acc[r2][2] = b0.z; acc[r2][3] = b0.w;
      acc[r2][4] = b1.x; acc[r2][5] = b1.y; acc[r2][6] = b1.z; acc[r2][7] = b1.w;
    }
  }
  #pragma unroll
  for (int ky = 0; ky < 7; ++ky) {
    #pragma unroll
    for (int kx = 0; kx < 7; ++kx) {
      const float4 w0 = *(const float4*)(wl + (ky * 7 + kx) * 32 + oc * 8);
      const float4 w1 = *(const float4*)(wl + (ky * 7 + kx) * 32 + oc * 8 + 4);
      #pragma unroll
      for (int r2 = 0; r2 < 4; ++r2) {
        s16x8 v = *(const s16x8*)(sl + ((r2 + ky) * 70 + (px + kx)) * 40 + oc * 8);
        acc[r2][0] += bf2f(v[0]) * w0.x; acc[r2][1] += bf2f(v[1]) * w0.y;
        acc[r2][2] += bf2f(v[2]) * w0.z; acc[r2][3] += bf2f(v[3]) * w0.w;
        acc[r2][4] += bf2f(v[4]) * w1.x; acc[r2][5] += bf2f(v[5]) * w1.y;
        acc[r2][6] += bf2f(v[6]) * w1.z; acc[r2][7] += bf2f(v[7]) * w1.w;
      }
    }
  }
  float ss = 0.f, qq = 0.f;
  #pragma unroll
  for (int r2 = 0; r2 < 4; ++r2) {
    int y = yt * 4 + r2;
    s16x8 o;
    #pragma unroll
    for (int j = 0; j < 8; ++j) {
      o[j] = f2bf(acc[r2][j]);
      float v = bf2f(o[j]);
      ss += v; qq += v * v;
    }
    *(s16x8*)(out + (size_t)((b * 64 + y) * 64 + px) * 256 + ck * 32 + oc * 8) = o;
  }
  // wave = one group (oc) x 64 px: full-wave butterfly, lane 0 writes.
  #pragma unroll
  for (int m = 1; m <= 32; m <<= 1) {
    ss += __shfl_xor(ss, m);
    qq += __shfl_xor(qq, m);
  }
  if ((t & 63) == 0)
    stats[(((size_t)b * 32 + ck * 4 + oc) << 5) + yt] = make_float2(ss, qq);
}

// Deformable conv v2 via MFMA, NHWC, px-split, XCD-swizzled (b = gid&7).
// Phase A: per-(px,k) bilinear weights/addresses once -> LDS table (9-stride).
// Phase B: gather+blend. Phase C: MFMA. (R19 verified, 134us.)
__global__ __launch_bounds__(256) void k_dcn_nhwc(const short* __restrict__ x,
    const short* __restrict__ co, const short* __restrict__ wf,
    const float* __restrict__ bias, float* __restrict__ out) {
  const int gid = blockIdx.x;
  const int b = gid & 7;
  const int r = gid >> 3;
  const int ph = r & 1, y = r >> 1;
  const int t = threadIdx.x;
  const int wid = t >> 6, l = t & 63;
  const int px0 = ph * 32;
  __shared__ __align__(16) short s2[9 * 32 * 40];
  __shared__ unsigned swt[288 * 9];   // [k*32+pxl]: w00..w11 (f32 bits), i00..i11
  f32x4 acc[4][2];
  #pragma unroll
  for (int i = 0; i < 4; ++i)
    #pragma unroll
    for (int j = 0; j < 2; ++j) acc[i][j] = (f32x4){0.f, 0.f, 0.f, 0.f};
  const short* xb = x + (size_t)b * 4096 * 256;
  for (int g = 0; g < 8; ++g) {
    __syncthreads();
    // phase A: 288 dense weight/address tasks (pxl, k)
    #pragma unroll
    for (int i = 0; i < 2; ++i) {
      int e2 = t + i * 256;
      if (e2 < 288) {
        int pxl = e2 & 31, k = e2 >> 5;
        int px = px0 + pxl;
        const short* cp = co + (size_t)(b * 4096 + y * 64 + px) * 256 + g * 32;
        float offy = bf2f(cp[2 * k]);
        float offx = bf2f(cp[2 * k + 1]);
        float mlog = bf2f(cp[18 + k]);
        float mv = 1.f / (1.f + __expf(-mlog));
        float py = offy + (float)(y - 1 + k / 3);
        float pxf = offx + (float)(px - 1 + k % 3);
        float y0f = floorf(py), x0f = floorf(pxf);
        float ly = py - y0f, lx = pxf - x0f;
        int y0 = (int)y0f, x0 = (int)x0f;
        int y1 = y0 + 1, x1 = x0 + 1;
        float fy0 = (y0 >= 0 && y0 < 64) ? 1.f : 0.f;
        float fy1 = (y1 >= 0 && y1 < 64) ? 1.f : 0.f;
        float fx0 = (x0 >= 0 && x0 < 64) ? 1.f : 0.f;
        float fx1 = (x1 >= 0 && x1 < 64) ? 1.f : 0.f;
        float w00 = (1.f - ly) * (1.f - lx) * fy0 * fx0 * mv;
        float w01 = (1.f - ly) * lx * fy0 * fx1 * mv;
        float w10 = ly * (1.f - lx) * fy1 * fx0 * mv;
        float w11 = ly * lx * fy1 * fx1 * mv;
        int y0c = min(63, max(0, y0)), y1c = min(63, max(0, y1));
        int x0c = min(63, max(0, x0)), x1c = min(63, max(0, x1));
        unsigned* wp = swt + e2 * 9;
        wp[0] = __float_as_uint(w00);
        wp[1] = __float_as_uint(w01);
        wp[2] = __float_as_uint(w10);
        wp[3] = __float_as_uint(w11);
        wp[4] = (unsigned)((y0c * 64 + x0c) * 256);
        wp[5] = (unsigned)((y0c * 64 + x1c) * 256);
        wp[6] = (unsigned)((y1c * 64 + x0c) * 256);
        wp[7] = (unsigned)((y1c * 64 + x1c) * 256);
      }
    }
    __syncthreads();
    // phase B: 1152 sampling tasks = 4 oct x 32 px x 9 k (gather + blend)
    #pragma unroll
    for (int i = 0; i < 5; ++i) {
      int e = t + i * 256;
      if (e < 1152) {
        int oct = e & 3, pxl = (e >> 2) & 31, k = e >> 7;
        const unsigned* wp = swt + (k * 32 + pxl) * 9;
        float w00 = __uint_as_float(wp[0]);
        float w01 = __uint_as_float(wp[1]);
        float w10 = __uint_as_float(wp[2]);
        float w11 = __uint_as_float(wp[3]);
        const short* xc = xb + g * 32 + oct * 8;
        s16x8 c00 = *(const s16x8*)(xc + wp[4]);
        s16x8 c01 = *(const s16x8*)(xc + wp[5]);
        s16x8 c10 = *(const s16x8*)(xc + wp[6]);
        s16x8 c11 = *(const s16x8*)(xc + wp[7]);
        s16x8 pk;
        #pragma unroll
        for (int cc = 0; cc < 8; ++cc) {
          float v = w00 * bf2f(c00[cc]) + w01 * bf2f(c01[cc])
                  + w10 * bf2f(c10[cc]) + w11 * bf2f(c11[cc]);
          pk[cc] = f2bf(v);
        }
        *(s16x8*)(s2 + (k * 32 + pxl) * 40 + oct * 8) = pk;
      }
    }
    __syncthreads();
    // phase C: MFMA (unchanged)
    #pragma unroll
    for (int k = 0; k < 9; ++k) {
      const int q = g * 9 + k;
      s16x8 afr[4], bfr[2];
      #pragma unroll
      for (int i = 0; i < 4; ++i)
        afr[i] = *(const s16x8*)(wf + (((size_t)q * 16 + wid * 4 + i) * 64 + l) * 8);
      #pragma unroll
      for (int jt = 0; jt < 2; ++jt)
        bfr[jt] = *(const s16x8*)(s2 + (k * 32 + jt * 16 + (l & 15)) * 40 + (l >> 4) * 8);
      #pragma unroll
      for (int i = 0; i < 4; ++i)
        #pragma unroll
        for (int jt = 0; jt < 2; ++jt)
          acc[i][jt] = __builtin_amdgcn_mfma_f32_16x16x32_bf16(
              afr[i], bfr[jt], acc[i][jt], 0, 0, 0);
    }
  }
  #pragma unroll
  for (int i = 0; i < 4; ++i) {
    int obase = wid * 64 + i * 16 + (l >> 4) * 4;
    #pragma unroll
    for (int jt = 0; jt < 2; ++jt) {
      int pxo = px0 + jt * 16 + (l & 15);
      #pragma unroll
      for (int rr = 0; rr < 4; ++rr) {
        int o = obase + rr;
        out[(((size_t)b * 256 + o) * 64 + y) * 64 + pxo] = acc[i][jt][rr] + bias[o];
      }
    }
  }
}

extern "C" void kernel_launch(void* const* d_in, const int* in_sizes, int n_in,
                              void* d_out, int out_size, void* d_ws, size_t ws_size,
                              hipStream_t stream) {
  const float* main_f = (const float*)d_in[0];
  const float* cond   = (const float*)d_in[1];
  const float* w1  = (const float*)d_in[2];
  const float* b1  = (const float*)d_in[3];
  const float* g1  = (const float*)d_in[4];
  const float* be1 = (const float*)d_in[5];
  const float* w2  = (const float*)d_in[6];
  const float* b2  = (const float*)d_in[7];
  const float* g2  = (const float*)d_in[8];
  const float* be2 = (const float*)d_in[9];
  const float* w3  = (const float*)d_in[10];
  const float* b3  = (const float*)d_in[11];
  const float* w4  = (const float*)d_in[12];
  const float* b4  = (const float*)d_in[13];
  const float* g3  = (const float*)d_in[14];
  const float* be3 = (const float*)d_in[15];
  const float* w_co  = (const float*)d_in[16];
  const float* b_co  = (const float*)d_in[17];
  const float* w_dcn = (const float*)d_in[18];
  const float* b_dcn = (const float*)d_in[19];

  float* out = (float*)d_out;
  float* warp_out = out;               // [8,256,64,64] f32 NCHW
  float* offset_feat = out + 8388608;  // [8,256,64,64] f32 NCHW

  short* ws = (short*)d_ws;
  short* bufA  = ws;                   // NHWC-512 conv1 input: 16777216
  short* Bb    = bufA + 16777216;      // NHWC-256: 8388608
  short* xbf   = Bb + 8388608;         // main NHWC-256 bf16: 8388608
  short* wfall = xbf + 8388608;        // contiguous: wf1 wf3 wf4 wfco wfdcn
  short* wf1   = wfall;                // 131072
  short* wf3   = wf1 + 131072;         // 65536
  short* wf4   = wf3 + 65536;          // 589824
  short* wfco  = wf4 + 589824;         // 589824
  short* wfdcn = wfco + 589824;        // 589824
  float2* parts2 = (float2*)(wfdcn + 589824);  // 8*32*32 float2 = 64KB

  auto cdiv = [](int a, int b) { return (a + b - 1) / b; };

  k_prep_all<<<cdiv(1966080, TPB), TPB, 0, stream>>>(w1, w3, w4, w_co, w_dcn, wfall);

  k_upsample_nhwc<<<cdiv(8 * 4096 * 256, TPB), TPB, 0, stream>>>(cond, bufA);
  dim3 gtr(64, 8, 8);
  k_main_tr<<<gtr, TPB, 0, stream>>>(main_f, xbf, bufA);

  // conv grids: 1D 1024 blocks, XCD-swizzled (b = gid&7)
  // conv1 (+GN1 stats in epilogue)
  k_conv2<<<1024, TPB, 0, stream>>>(bufA, 512, 256, 1, wf1, b1, Bb, 0, parts2);
  k_gn_apply<<<2048, TPB, 0, stream>>>(Bb, nullptr, parts2, 32, g1, be1);
  // dw7 (+GN2 stats in epilogue, 16 yt-partials)
  k_dw7_nhwc<<<1024, TPB, 0, stream>>>(Bb, w2, b2, bufA, parts2);
  k_gn_apply<<<2048, TPB, 0, stream>>>(bufA, nullptr, parts2, 16, g2, be2);
  // conv3 (no stats)
  k_conv2<<<1024, TPB, 0, stream>>>(bufA, 256, 256, 1, wf3, b3, Bb, 0, nullptr);
  // conv4 (+GN3 stats in epilogue)
  k_conv2<<<1024, TPB, 0, stream>>>(Bb, 256, 256, 9, wf4, b4, bufA, 0, parts2);
  k_gn_apply<<<2048, TPB, 0, stream>>>(bufA, offset_feat, parts2, 32, g3, be3);
  // conv_offset: 3x3 256->216, channel-permuted NHWC-256 co (no stats)
  k_conv2<<<1024, TPB, 0, stream>>>(bufA, 256, 216, 9, wfco, b_co, Bb, 1, nullptr);
  // deformable conv -> warp (output 0)
  k_dcn_nhwc<<<1024, TPB, 0, stream>>>(xbf, Bb, wfdcn, b_dcn, warp_out);
}

// Round 24
// 433.314 us; speedup vs baseline: 1.0621x; 1.0134x over previous
//
#include <hip/hip_runtime.h>
#include <cstdint>

#define TPB 256

typedef __attribute__((ext_vector_type(8))) short s16x8;
typedef __attribute__((ext_vector_type(4))) short s16x4;
typedef __attribute__((ext_vector_type(4))) float f32x4;

__device__ __forceinline__ float silu_f(float x) { return x / (1.f + __expf(-x)); }

__device__ __forceinline__ short f2bf(float f) {
  union { float f; unsigned u; } v; v.f = f;
  unsigned r = v.u + 0x7fffu + ((v.u >> 16) & 1u);
  return (short)(r >> 16);
}
__device__ __forceinline__ float bf2f(short s) {
  union { unsigned u; float f; } v;
  v.u = ((unsigned)(unsigned short)s) << 16;
  return v.f;
}

// All conv weights -> MFMA A-fragment order (bf16), one kernel.  (math verified R3)
__global__ void k_prep_all(const float* __restrict__ w1, const float* __restrict__ w3,
                           const float* __restrict__ w4, const float* __restrict__ wco,
                           const float* __restrict__ wdcn, short* __restrict__ dst) {
  int idx = blockIdx.x * TPB + threadIdx.x;
  if (idx >= 1966080) return;
  const float* w; int Cout, Cin, taps, mode; int local = idx;
  if (idx < 131072)       { w = w1;   Cout = 256; Cin = 512; taps = 1; mode = 0; }
  else if (idx < 196608)  { w = w3;   local -= 131072;  Cout = 256; Cin = 256; taps = 1; mode = 0; }
  else if (idx < 786432)  { w = w4;   local -= 196608;  Cout = 256; Cin = 256; taps = 9; mode = 0; }
  else if (idx < 1376256) { w = wco;  local -= 786432;  Cout = 216; Cin = 256; taps = 9; mode = 0; }
  else                    { w = wdcn; local -= 1376256; Cout = 256; Cin = 256; taps = 9; mode = 1; }
  int j = local & 7;
  int l = (local >> 3) & 63;
  int ot = (local >> 9) & 15;
  int q = local >> 13;
  int tap, cb;
  if (mode == 0) { int ncb = Cin >> 5; tap = q / ncb; cb = q - tap * ncb; }
  else           { tap = q % 9; cb = q / 9; }
  int o = ot * 16 + (l & 15);
  int c = cb * 32 + ((l >> 4) & 3) * 8 + j;
  float v = 0.f;
  if (o < Cout && c < Cin) v = w[((size_t)o * Cin + c) * taps + tap];
  dst[idx] = f2bf(v);
}

// bilinear 16x16 -> 64x64 (half-pixel, edge clamp), write NHWC-512 channels 0..255
__global__ void k_upsample_nhwc(const float* __restrict__ in, short* __restrict__ outA) {
  int idx = blockIdx.x * TPB + threadIdx.x;
  if (idx >= 8 * 4096 * 256) return;
  int c = idx & 255;
  int p = idx >> 8;          // (b*4096 + y*64 + x)
  int b = p >> 12;
  int rem = p & 4095;
  int y = rem >> 6, x = rem & 63;
  float sy = (y + 0.5f) * 0.25f - 0.5f;
  float sx = (x + 0.5f) * 0.25f - 0.5f;
  float y0f = floorf(sy), x0f = floorf(sx);
  float ly = sy - y0f, lx = sx - x0f;
  int y0 = (int)y0f, x0 = (int)x0f;
  int y0c = min(15, max(0, y0)), y1c = min(15, max(0, y0 + 1));
  int x0c = min(15, max(0, x0)), x1c = min(15, max(0, x0 + 1));
  const float* src = in + (size_t)(b * 256 + c) * 256;
  float v00 = src[y0c * 16 + x0c], v01 = src[y0c * 16 + x1c];
  float v10 = src[y1c * 16 + x0c], v11 = src[y1c * 16 + x1c];
  float r = (1.f - ly) * ((1.f - lx) * v00 + lx * v01)
          + ly * ((1.f - lx) * v10 + lx * v11);
  outA[(size_t)p * 512 + c] = f2bf(r);
}

// main f32 NCHW -> bf16 NHWC-256 (xbf) + NHWC-512 ch 256..511 (conv1 input).
__global__ __launch_bounds__(256) void k_main_tr(const float* __restrict__ in,
    short* __restrict__ xbf, short* __restrict__ outA) {
  const int pc = blockIdx.x, ck = blockIdx.y, b = blockIdx.z;
  __shared__ float sl[32][66];
  const int t = threadIdx.x;
  const int pxl = t & 63, cs = t >> 6;
  const float* src = in + (size_t)(b * 256 + ck * 32) * 4096 + pc * 64;
  #pragma unroll
  for (int i = 0; i < 8; ++i) {
    int c = i * 4 + cs;
    sl[c][pxl] = src[(size_t)c * 4096 + pxl];
  }
  __syncthreads();
  const int oct = (t & 3) * 8, px2 = t >> 2;
  s16x8 v;
  #pragma unroll
  for (int j = 0; j < 8; ++j) v[j] = f2bf(sl[oct + j][px2]);
  size_t p = (size_t)b * 4096 + pc * 64 + px2;
  *(s16x8*)(xbf + p * 256 + ck * 32 + oct) = v;
  *(s16x8*)(outA + p * 512 + 256 + ck * 32 + oct) = v;
}

// NHWC MFMA conv, 2-row x 128-o blocks, 512 threads (8 waves), XCD-swizzled
// 1D grid (b = gid&7). r = gid>>3: ogh = r&1 (128-o half), yt = r>>1 (2 rows).
// Halves staging redundancy vs 64-o blocks (2 blocks/(yt,b) instead of 4).
// stats != nullptr (non-remap only): epilogue accumulates per-(b,group,yt)
// {sum,sumsq} of the STORED bf16 output via shfl_xor butterfly + LDS combine.
__global__ __launch_bounds__(512) void k_conv2(
    const short* __restrict__ in, int Cin, int Cout, int taps,
    const short* __restrict__ wf, const float* __restrict__ bias,
    short* __restrict__ out, int remap, float2* __restrict__ stats) {
  const int gid = blockIdx.x;
  const int b = gid & 7;
  const int r = gid >> 3;
  const int ogh = r & 1, yt = r >> 1;
  const int t = threadIdx.x;
  const int wid = t >> 6, l = t & 63;
  const int wo = wid >> 1, wr = wid & 1;
  const int pd = (taps == 9) ? 1 : 0;
  const int rows_in = 2 + 2 * pd;              // 2 or 4
  const int pxw = 64 + 2 * pd;                 // 64 or 66
  const int ncb = Cin >> 5;
  const int nchunk = Cin >> 6;
  const int ndy = (taps == 9) ? 3 : 1;
  __shared__ __align__(16) short sl[4 * 66 * 68];
  __shared__ float sred[2][16][2];
  f32x4 acc[2][4];
  #pragma unroll
  for (int i = 0; i < 2; ++i)
    #pragma unroll
    for (int j = 0; j < 4; ++j) acc[i][j] = (f32x4){0.f, 0.f, 0.f, 0.f};
  const int y0g = yt * 2 - pd;                 // global row of LDS row 0
  for (int chunk = 0; chunk < nchunk; ++chunk) {
    __syncthreads();
    {
      const int nun = rows_in * pxw * 8;       // s16x8 units (max 2112)
      const int c0 = chunk * 64;
      #pragma unroll
      for (int i = 0; i < 5; ++i) {
        int e = t + i * 512;
        if (e < nun) {
          int oct = e & 7;
          int pe = e >> 3;
          int pxs = pe % pxw;
          int row = pe / pxw;
          int yy = y0g + row, xx = pxs - pd;
          s16x8 v = {0, 0, 0, 0, 0, 0, 0, 0};
          if (yy >= 0 && yy < 64 && xx >= 0 && xx < 64)
            v = *(const s16x8*)(in + (size_t)((b * 64 + yy) * 64 + xx) * Cin
                                + c0 + oct * 8);
          *(s16x8*)(sl + (row * 66 + pxs) * 68 + oct * 8) = v;
        }
      }
    }
    __syncthreads();
    #pragma unroll 2
    for (int cb = 0; cb < 2; ++cb) {
      const int qc = chunk * 2 + cb;
      for (int dyi = 0; dyi < ndy; ++dyi) {
        const int lrow = wr + dyi;            // LDS row (wr+dy+pd)
        for (int dxi = 0; dxi < ndy; ++dxi) {
          const int tap = (taps == 9) ? dyi * 3 + dxi : 0;
          const int q = tap * ncb + qc;
          s16x8 afr[2];
          #pragma unroll
          for (int i = 0; i < 2; ++i) {
            int ot = ogh * 8 + wo * 2 + i;
            afr[i] = *(const s16x8*)(wf + (((size_t)q * 16 + ot) * 64 + l) * 8);
          }
          #pragma unroll
          for (int jt = 0; jt < 4; ++jt) {
            int pxi = jt * 16 + (l & 15) + dxi;   // dx+pd = dxi
            s16x8 bfr = *(const s16x8*)(sl + (lrow * 66 + pxi) * 68
                                        + cb * 32 + (l >> 4) * 8);
            #pragma unroll
            for (int i = 0; i < 2; ++i)
              acc[i][jt] = __builtin_amdgcn_mfma_f32_16x16x32_bf16(
                  afr[i], bfr, acc[i][jt], 0, 0, 0);
          }
        }
      }
    }
  }
  const int y = yt * 2 + wr;
  float ss[2] = {0.f, 0.f}, qq[2] = {0.f, 0.f};
  #pragma unroll
  for (int i = 0; i < 2; ++i) {
    #pragma unroll
    for (int jt = 0; jt < 4; ++jt) {
      int px = jt * 16 + (l & 15);
      int obase = ogh * 128 + wo * 32 + i * 16 + (l >> 4) * 4;
      size_t pbase = (size_t)((b * 64 + y) * 64 + px) * (remap ? 256 : Cout);
      if (!remap) {
        s16x4 r2;
        #pragma unroll
        for (int rr = 0; rr < 4; ++rr) {
          r2[rr] = f2bf(acc[i][jt][rr] + bias[obase + rr]);
          if (stats) { float v = bf2f(r2[rr]); ss[i] += v; qq[i] += v * v; }
        }
        *(s16x4*)(out + pbase + obase) = r2;
      } else {
        #pragma unroll
        for (int rr = 0; rr < 4; ++rr) {
          int o = obase + rr;
          if (o < Cout) {
            int op;
            if (o < 144) op = (o / 18) * 32 + (o % 18);
            else { int jj = o - 144; op = (jj / 9) * 32 + 18 + (jj % 9); }
            out[pbase + op] = f2bf(acc[i][jt][rr] + bias[o]);
          }
        }
      }
    }
  }
  if (stats && !remap) {
    // butterfly within each 32-lane half (lanes 0-31: ch-sub 0-7; 32-63: 8-15)
    #pragma unroll
    for (int i = 0; i < 2; ++i) {
      float s = ss[i], q = qq[i];
      #pragma unroll
      for (int m = 1; m <= 16; m <<= 1) {
        s += __shfl_xor(s, m);
        q += __shfl_xor(q, m);
      }
      if ((l & 31) == 0) {
        int gl = wo * 4 + i * 2 + (l >> 5);   // local group 0..15
        sred[wr][gl][0] = s;
        sred[wr][gl][1] = q;
      }
    }
    __syncthreads();
    if (t < 16) {
      float S = sred[0][t][0] + sred[1][t][0];
      float Q = sred[0][t][1] + sred[1][t][1];
      stats[(((size_t)b * 32 + ogh * 16 + t) << 5) + yt] = make_float2(S, Q);
    }
  }
}

// GroupNorm apply + SiLU: reduces np yt-partials of (b,g) in fixed order,
// applies to its 512 px x 8 ch slice in-place (bf16) + optional f32 NCHW out.
__global__ __launch_bounds__(256) void k_gn_apply(short* __restrict__ io,
    float* __restrict__ f32out, const float2* __restrict__ parts, int np,
    const float* __restrict__ gamma, const float* __restrict__ beta) {
  const int gid = blockIdx.x;
  const int b = gid & 7;
  const int r = gid >> 3;
  const int ck = r & 7, g = r >> 3;
  const int t = threadIdx.x;
  float S = 0.f, Q = 0.f;
  const float2* pp = parts + (((size_t)b * 32 + g) << 5);
  for (int i = 0; i < np; ++i) { float2 p = pp[i]; S += p.x; Q += p.y; }
  const float mean = S * (1.f / 32768.f);
  const float var = Q * (1.f / 32768.f) - mean * mean;
  const float rs = rsqrtf(var + 1e-6f);
  float ga[8], bb[8];
  #pragma unroll
  for (int j = 0; j < 8; ++j) {
    ga[j] = gamma[g * 8 + j] * rs;
    bb[j] = beta[g * 8 + j] - mean * ga[j];
  }
  #pragma unroll
  for (int i = 0; i < 2; ++i) {
    int e = ck * 512 + t + i * 256;
    short* ptr = io + (size_t)(b * 4096 + e) * 256 + g * 8;
    s16x8 v = *(const s16x8*)ptr;
    s16x8 r2;
    #pragma unroll
    for (int j = 0; j < 8; ++j) {
      float o = silu_f(bf2f(v[j]) * ga[j] + bb[j]);
      r2[j] = f2bf(o);
      if (f32out) f32out[(size_t)(b * 256 + g * 8 + j) * 4096 + e] = o;
    }
    *(s16x8*)ptr = r2;
  }
}

// depthwise 7x7 pad 3, NHWC bf16, LDS-staged, XCD-swizzled 1D grid.
// stats: per-(b,group,yt) {sum,sumsq} of stored output (wave = 1 group x 64 px).
__global__ __launch_bounds__(256) void k_dw7_nhwc(const short* __restrict__ in,
    const float* __restrict__ w, const float* __restrict__ bias,
    short* __restrict__ out, float2* __restrict__ stats) {
  const int gid = blockIdx.x;
  const int b = gid & 7;
  const int r = gid >> 3;
  const int ck = r & 7, yt = r >> 3;
  const int t = threadIdx.x;
  const int px = t & 63, oc = t >> 6;
  __shared__ __align__(16) short sl[10 * 70 * 40];
  __shared__ float wl[49 * 32];
  for (int e = t; e < 49 * 32; e += TPB) {
    int tap = e >> 5, cc = e & 31;
    wl[tap * 32 + cc] = w[(ck * 32 + cc) * 49 + tap];
  }
  const int y0in = yt * 4 - 3;
  #pragma unroll
  for (int i = 0; i < 11; ++i) {
    int e = t + i * TPB;
    if (e < 2800) {
      int oc2 = e & 3;
      int pe = e >> 2;
      int pxs = pe % 70;
      int row = pe / 70;
      int yy = y0in + row, xx = pxs - 3;
      s16x8 v = {0, 0, 0, 0, 0, 0, 0, 0};
      if (yy >= 0 && yy < 64 && xx >= 0 && xx < 64)
        v = *(const s16x8*)(in + (size_t)((b * 64 + yy) * 64 + xx) * 256
                            + ck * 32 + oc2 * 8);
      *(s16x8*)(sl + (row * 70 + pxs) * 40 + oc2 * 8) = v;
    }
  }
  __syncthreads();
  float acc[4][8];
  {
    float4 b0 = *(const float4*)(bias + ck * 32 + oc * 8);
    float4 b1 = *(const float4*)(bias + ck * 32 + oc * 8 + 4);
    #pragma unroll
    for (int r2 = 0; r2 < 4; ++r2) {
      acc[r2][0] = b0.x; acc[r2][1] = b0.y; acc[r2][2] = b0.z; acc[r2][3] = b0.w;
      acc[r2][4] = b1.x; acc[r2][5] = b1.y; acc[r2][6] = b1.z; acc[r2][7] = b1.w;
    }
  }
  #pragma unroll
  for (int ky = 0; ky < 7; ++ky) {
    #pragma unroll
    for (int kx = 0; kx < 7; ++kx) {
      const float4 w0 = *(const float4*)(wl + (ky * 7 + kx) * 32 + oc * 8);
      const float4 w1 = *(const float4*)(wl + (ky * 7 + kx) * 32 + oc * 8 + 4);
      #pragma unroll
      for (int r2 = 0; r2 < 4; ++r2) {
        s16x8 v = *(const s16x8*)(sl + ((r2 + ky) * 70 + (px + kx)) * 40 + oc * 8);
        acc[r2][0] += bf2f(v[0]) * w0.x; acc[r2][1] += bf2f(v[1]) * w0.y;
        acc[r2][2] += bf2f(v[2]) * w0.z; acc[r2][3] += bf2f(v[3]) * w0.w;
        acc[r2][4] += bf2f(v[4]) * w1.x; acc[r2][5] += bf2f(v[5]) * w1.y;
        acc[r2][6] += bf2f(v[6]) * w1.z; acc[r2][7] += bf2f(v[7]) * w1.w;
      }
    }
  }
  float ss = 0.f, qq = 0.f;
  #pragma unroll
  for (int r2 = 0; r2 < 4; ++r2) {
    int y = yt * 4 + r2;
    s16x8 o;
    #pragma unroll
    for (int j = 0; j < 8; ++j) {
      o[j] = f2bf(acc[r2][j]);
      float v = bf2f(o[j]);
      ss += v; qq += v * v;
    }
    *(s16x8*)(out + (size_t)((b * 64 + y) * 64 + px) * 256 + ck * 32 + oc * 8) = o;
  }
  // wave = one group (oc) x 64 px: full-wave butterfly, lane 0 writes.
  #pragma unroll
  for (int m = 1; m <= 32; m <<= 1) {
    ss += __shfl_xor(ss, m);
    qq += __shfl_xor(qq, m);
  }
  if ((t & 63) == 0)
    stats[(((size_t)b * 32 + ck * 4 + oc) << 5) + yt] = make_float2(ss, qq);
}

// Deformable conv v2 via MFMA, NHWC, px-split, XCD-swizzled (b = gid&7).
// Phase A: per-(px,k) bilinear weights/addresses once -> LDS table (9-stride).
// Phase B: gather+blend. Phase C: MFMA. (R19 verified, 134us.)
__global__ __launch_bounds__(256) void k_dcn_nhwc(const short* __restrict__ x,
    const short* __restrict__ co, const short* __restrict__ wf,
    const float* __restrict__ bias, float* __restrict__ out) {
  const int gid = blockIdx.x;
  const int b = gid & 7;
  const int r = gid >> 3;
  const int ph = r & 1, y = r >> 1;
  const int t = threadIdx.x;
  const int wid = t >> 6, l = t & 63;
  const int px0 = ph * 32;
  __shared__ __align__(16) short s2[9 * 32 * 40];
  __shared__ unsigned swt[288 * 9];   // [k*32+pxl]: w00..w11 (f32 bits), i00..i11
  f32x4 acc[4][2];
  #pragma unroll
  for (int i = 0; i < 4; ++i)
    #pragma unroll
    for (int j = 0; j < 2; ++j) acc[i][j] = (f32x4){0.f, 0.f, 0.f, 0.f};
  const short* xb = x + (size_t)b * 4096 * 256;
  for (int g = 0; g < 8; ++g) {
    __syncthreads();
    // phase A: 288 dense weight/address tasks (pxl, k)
    #pragma unroll
    for (int i = 0; i < 2; ++i) {
      int e2 = t + i * 256;
      if (e2 < 288) {
        int pxl = e2 & 31, k = e2 >> 5;
        int px = px0 + pxl;
        const short* cp = co + (size_t)(b * 4096 + y * 64 + px) * 256 + g * 32;
        float offy = bf2f(cp[2 * k]);
        float offx = bf2f(cp[2 * k + 1]);
        float mlog = bf2f(cp[18 + k]);
        float mv = 1.f / (1.f + __expf(-mlog));
        float py = offy + (float)(y - 1 + k / 3);
        float pxf = offx + (float)(px - 1 + k % 3);
        float y0f = floorf(py), x0f = floorf(pxf);
        float ly = py - y0f, lx = pxf - x0f;
        int y0 = (int)y0f, x0 = (int)x0f;
        int y1 = y0 + 1, x1 = x0 + 1;
        float fy0 = (y0 >= 0 && y0 < 64) ? 1.f : 0.f;
        float fy1 = (y1 >= 0 && y1 < 64) ? 1.f : 0.f;
        float fx0 = (x0 >= 0 && x0 < 64) ? 1.f : 0.f;
        float fx1 = (x1 >= 0 && x1 < 64) ? 1.f : 0.f;
        float w00 = (1.f - ly) * (1.f - lx) * fy0 * fx0 * mv;
        float w01 = (1.f - ly) * lx * fy0 * fx1 * mv;
        float w10 = ly * (1.f - lx) * fy1 * fx0 * mv;
        float w11 = ly * lx * fy1 * fx1 * mv;
        int y0c = min(63, max(0, y0)), y1c = min(63, max(0, y1));
        int x0c = min(63, max(0, x0)), x1c = min(63, max(0, x1));
        unsigned* wp = swt + e2 * 9;
        wp[0] = __float_as_uint(w00);
        wp[1] = __float_as_uint(w01);
        wp[2] = __float_as_uint(w10);
        wp[3] = __float_as_uint(w11);
        wp[4] = (unsigned)((y0c * 64 + x0c) * 256);
        wp[5] = (unsigned)((y0c * 64 + x1c) * 256);
        wp[6] = (unsigned)((y1c * 64 + x0c) * 256);
        wp[7] = (unsigned)((y1c * 64 + x1c) * 256);
      }
    }
    __syncthreads();
    // phase B: 1152 sampling tasks = 4 oct x 32 px x 9 k (gather + blend)
    #pragma unroll
    for (int i = 0; i < 5; ++i) {
      int e = t + i * 256;
      if (e < 1152) {
        int oct = e & 3, pxl = (e >> 2) & 31, k = e >> 7;
        const unsigned* wp = swt + (k * 32 + pxl) * 9;
        float w00 = __uint_as_float(wp[0]);
        float w01 = __uint_as_float(wp[1]);
        float w10 = __uint_as_float(wp[2]);
        float w11 = __uint_as_float(wp[3]);
        const short* xc = xb + g * 32 + oct * 8;
        s16x8 c00 = *(const s16x8*)(xc + wp[4]);
        s16x8 c01 = *(const s16x8*)(xc + wp[5]);
        s16x8 c10 = *(const s16x8*)(xc + wp[6]);
        s16x8 c11 = *(const s16x8*)(xc + wp[7]);
        s16x8 pk;
        #pragma unroll
        for (int cc = 0; cc < 8; ++cc) {
          float v = w00 * bf2f(c00[cc]) + w01 * bf2f(c01[cc])
                  + w10 * bf2f(c10[cc]) + w11 * bf2f(c11[cc]);
          pk[cc] = f2bf(v);
        }
        *(s16x8*)(s2 + (k * 32 + pxl) * 40 + oct * 8) = pk;
      }
    }
    __syncthreads();
    // phase C: MFMA (unchanged)
    #pragma unroll
    for (int k = 0; k < 9; ++k) {
      const int q = g * 9 + k;
      s16x8 afr[4], bfr[2];
      #pragma unroll
      for (int i = 0; i < 4; ++i)
        afr[i] = *(const s16x8*)(wf + (((size_t)q * 16 + wid * 4 + i) * 64 + l) * 8);
      #pragma unroll
      for (int jt = 0; jt < 2; ++jt)
        bfr[jt] = *(const s16x8*)(s2 + (k * 32 + jt * 16 + (l & 15)) * 40 + (l >> 4) * 8);
      #pragma unroll
      for (int i = 0; i < 4; ++i)
        #pragma unroll
        for (int jt = 0; jt < 2; ++jt)
          acc[i][jt] = __builtin_amdgcn_mfma_f32_16x16x32_bf16(
              afr[i], bfr[jt], acc[i][jt], 0, 0, 0);
    }
  }
  #pragma unroll
  for (int i = 0; i < 4; ++i) {
    int obase = wid * 64 + i * 16 + (l >> 4) * 4;
    #pragma unroll
    for (int jt = 0; jt < 2; ++jt) {
      int pxo = px0 + jt * 16 + (l & 15);
      #pragma unroll
      for (int rr = 0; rr < 4; ++rr) {
        int o = obase + rr;
        out[(((size_t)b * 256 + o) * 64 + y) * 64 + pxo] = acc[i][jt][rr] + bias[o];
      }
    }
  }
}

extern "C" void kernel_launch(void* const* d_in, const int* in_sizes, int n_in,
                              void* d_out, int out_size, void* d_ws, size_t ws_size,
                              hipStream_t stream) {
  const float* main_f = (const float*)d_in[0];
  const float* cond   = (const float*)d_in[1];
  const float* w1  = (const float*)d_in[2];
  const float* b1  = (const float*)d_in[3];
  const float* g1  = (const float*)d_in[4];
  const float* be1 = (const float*)d_in[5];
  const float* w2  = (const float*)d_in[6];
  const float* b2  = (const float*)d_in[7];
  const float* g2  = (const float*)d_in[8];
  const float* be2 = (const float*)d_in[9];
  const float* w3  = (const float*)d_in[10];
  const float* b3  = (const float*)d_in[11];
  const float* w4  = (const float*)d_in[12];
  const float* b4  = (const float*)d_in[13];
  const float* g3  = (const float*)d_in[14];
  const float* be3 = (const float*)d_in[15];
  const float* w_co  = (const float*)d_in[16];
  const float* b_co  = (const float*)d_in[17];
  const float* w_dcn = (const float*)d_in[18];
  const float* b_dcn = (const float*)d_in[19];

  float* out = (float*)d_out;
  float* warp_out = out;               // [8,256,64,64] f32 NCHW
  float* offset_feat = out + 8388608;  // [8,256,64,64] f32 NCHW

  short* ws = (short*)d_ws;
  short* bufA  = ws;                   // NHWC-512 conv1 input: 16777216
  short* Bb    = bufA + 16777216;      // NHWC-256: 8388608
  short* xbf   = Bb + 8388608;         // main NHWC-256 bf16: 8388608
  short* wfall = xbf + 8388608;        // contiguous: wf1 wf3 wf4 wfco wfdcn
  short* wf1   = wfall;                // 131072
  short* wf3   = wf1 + 131072;         // 65536
  short* wf4   = wf3 + 65536;          // 589824
  short* wfco  = wf4 + 589824;         // 589824
  short* wfdcn = wfco + 589824;        // 589824
  float2* parts2 = (float2*)(wfdcn + 589824);  // 8*32*32 float2 = 64KB

  auto cdiv = [](int a, int b) { return (a + b - 1) / b; };

  k_prep_all<<<cdiv(1966080, TPB), TPB, 0, stream>>>(w1, w3, w4, w_co, w_dcn, wfall);

  k_upsample_nhwc<<<cdiv(8 * 4096 * 256, TPB), TPB, 0, stream>>>(cond, bufA);
  dim3 gtr(64, 8, 8);
  k_main_tr<<<gtr, TPB, 0, stream>>>(main_f, xbf, bufA);

  // conv grids: 1D 512 blocks x 512 threads, XCD-swizzled (b = gid&7)
  // conv1 (+GN1 stats in epilogue)
  k_conv2<<<512, 512, 0, stream>>>(bufA, 512, 256, 1, wf1, b1, Bb, 0, parts2);
  k_gn_apply<<<2048, TPB, 0, stream>>>(Bb, nullptr, parts2, 32, g1, be1);
  // dw7 (+GN2 stats in epilogue, 16 yt-partials)
  k_dw7_nhwc<<<1024, TPB, 0, stream>>>(Bb, w2, b2, bufA, parts2);
  k_gn_apply<<<2048, TPB, 0, stream>>>(bufA, nullptr, parts2, 16, g2, be2);
  // conv3 (no stats)
  k_conv2<<<512, 512, 0, stream>>>(bufA, 256, 256, 1, wf3, b3, Bb, 0, nullptr);
  // conv4 (+GN3 stats in epilogue)
  k_conv2<<<512, 512, 0, stream>>>(Bb, 256, 256, 9, wf4, b4, bufA, 0, parts2);
  k_gn_apply<<<2048, TPB, 0, stream>>>(bufA, offset_feat, parts2, 32, g3, be3);
  // conv_offset: 3x3 256->216, channel-permuted NHWC-256 co (no stats)
  k_conv2<<<512, 512, 0, stream>>>(bufA, 256, 216, 9, wfco, b_co, Bb, 1, nullptr);
  // deformable conv -> warp (output 0)
  k_dcn_nhwc<<<1024, TPB, 0, stream>>>(xbf, Bb, wfdcn, b_dcn, warp_out);
}

// Round 25
// 430.517 us; speedup vs baseline: 1.0690x; 1.0065x over previous
//
#include <hip/hip_runtime.h>
#include <cstdint>

#define TPB 256

typedef __attribute__((ext_vector_type(8))) short s16x8;
typedef __attribute__((ext_vector_type(4))) short s16x4;
typedef __attribute__((ext_vector_type(4))) float f32x4;

__device__ __forceinline__ float silu_f(float x) { return x / (1.f + __expf(-x)); }

__device__ __forceinline__ short f2bf(float f) {
  union { float f; unsigned u; } v; v.f = f;
  unsigned r = v.u + 0x7fffu + ((v.u >> 16) & 1u);
  return (short)(r >> 16);
}
__device__ __forceinline__ float bf2f(short s) {
  union { unsigned u; float f; } v;
  v.u = ((unsigned)(unsigned short)s) << 16;
  return v.f;
}

// All conv weights -> MFMA A-fragment order (bf16), one kernel.  (math verified R3)
__global__ void k_prep_all(const float* __restrict__ w1, const float* __restrict__ w3,
                           const float* __restrict__ w4, const float* __restrict__ wco,
                           const float* __restrict__ wdcn, short* __restrict__ dst) {
  int idx = blockIdx.x * TPB + threadIdx.x;
  if (idx >= 1966080) return;
  const float* w; int Cout, Cin, taps, mode; int local = idx;
  if (idx < 131072)       { w = w1;   Cout = 256; Cin = 512; taps = 1; mode = 0; }
  else if (idx < 196608)  { w = w3;   local -= 131072;  Cout = 256; Cin = 256; taps = 1; mode = 0; }
  else if (idx < 786432)  { w = w4;   local -= 196608;  Cout = 256; Cin = 256; taps = 9; mode = 0; }
  else if (idx < 1376256) { w = wco;  local -= 786432;  Cout = 216; Cin = 256; taps = 9; mode = 0; }
  else                    { w = wdcn; local -= 1376256; Cout = 256; Cin = 256; taps = 9; mode = 1; }
  int j = local & 7;
  int l = (local >> 3) & 63;
  int ot = (local >> 9) & 15;
  int q = local >> 13;
  int tap, cb;
  if (mode == 0) { int ncb = Cin >> 5; tap = q / ncb; cb = q - tap * ncb; }
  else           { tap = q % 9; cb = q / 9; }
  int o = ot * 16 + (l & 15);
  int c = cb * 32 + ((l >> 4) & 3) * 8 + j;
  float v = 0.f;
  if (o < Cout && c < Cin) v = w[((size_t)o * Cin + c) * taps + tap];
  dst[idx] = f2bf(v);
}

// bilinear 16x16 -> 64x64 (half-pixel, edge clamp), write NHWC-512 channels 0..255
__global__ void k_upsample_nhwc(const float* __restrict__ in, short* __restrict__ outA) {
  int idx = blockIdx.x * TPB + threadIdx.x;
  if (idx >= 8 * 4096 * 256) return;
  int c = idx & 255;
  int p = idx >> 8;          // (b*4096 + y*64 + x)
  int b = p >> 12;
  int rem = p & 4095;
  int y = rem >> 6, x = rem & 63;
  float sy = (y + 0.5f) * 0.25f - 0.5f;
  float sx = (x + 0.5f) * 0.25f - 0.5f;
  float y0f = floorf(sy), x0f = floorf(sx);
  float ly = sy - y0f, lx = sx - x0f;
  int y0 = (int)y0f, x0 = (int)x0f;
  int y0c = min(15, max(0, y0)), y1c = min(15, max(0, y0 + 1));
  int x0c = min(15, max(0, x0)), x1c = min(15, max(0, x0 + 1));
  const float* src = in + (size_t)(b * 256 + c) * 256;
  float v00 = src[y0c * 16 + x0c], v01 = src[y0c * 16 + x1c];
  float v10 = src[y1c * 16 + x0c], v11 = src[y1c * 16 + x1c];
  float r = (1.f - ly) * ((1.f - lx) * v00 + lx * v01)
          + ly * ((1.f - lx) * v10 + lx * v11);
  outA[(size_t)p * 512 + c] = f2bf(r);
}

// main f32 NCHW -> bf16 NHWC-256 (xbf) + NHWC-512 ch 256..511 (conv1 input).
__global__ __launch_bounds__(256) void k_main_tr(const float* __restrict__ in,
    short* __restrict__ xbf, short* __restrict__ outA) {
  const int pc = blockIdx.x, ck = blockIdx.y, b = blockIdx.z;
  __shared__ float sl[32][66];
  const int t = threadIdx.x;
  const int pxl = t & 63, cs = t >> 6;
  const float* src = in + (size_t)(b * 256 + ck * 32) * 4096 + pc * 64;
  #pragma unroll
  for (int i = 0; i < 8; ++i) {
    int c = i * 4 + cs;
    sl[c][pxl] = src[(size_t)c * 4096 + pxl];
  }
  __syncthreads();
  const int oct = (t & 3) * 8, px2 = t >> 2;
  s16x8 v;
  #pragma unroll
  for (int j = 0; j < 8; ++j) v[j] = f2bf(sl[oct + j][px2]);
  size_t p = (size_t)b * 4096 + pc * 64 + px2;
  *(s16x8*)(xbf + p * 256 + ck * 32 + oct) = v;
  *(s16x8*)(outA + p * 512 + 256 + ck * 32 + oct) = v;
}

// NHWC MFMA conv, 2-row x 256-o blocks, 1024 threads (16 waves), XCD-swizzled
// 1D grid (b = gid&7). yt = gid>>3 (2 rows). Staging redundancy = 1x (each
// (yt,b) slab staged exactly once). Per-wave: wo = wid>>1 (0..7), wr = wid&1.
// stats != nullptr (non-remap only): epilogue accumulates per-(b,group,yt)
// {sum,sumsq} of the STORED bf16 output via shfl_xor butterfly + LDS combine.
__global__ __launch_bounds__(1024) void k_conv2(
    const short* __restrict__ in, int Cin, int Cout, int taps,
    const short* __restrict__ wf, const float* __restrict__ bias,
    short* __restrict__ out, int remap, float2* __restrict__ stats) {
  const int gid = blockIdx.x;
  const int b = gid & 7;
  const int yt = gid >> 3;
  const int t = threadIdx.x;
  const int wid = t >> 6, l = t & 63;
  const int wo = wid >> 1, wr = wid & 1;
  const int pd = (taps == 9) ? 1 : 0;
  const int rows_in = 2 + 2 * pd;              // 2 or 4
  const int pxw = 64 + 2 * pd;                 // 64 or 66
  const int ncb = Cin >> 5;
  const int nchunk = Cin >> 6;
  const int ndy = (taps == 9) ? 3 : 1;
  __shared__ __align__(16) short sl[4 * 66 * 68];
  __shared__ float sred[2][32][2];
  f32x4 acc[2][4];
  #pragma unroll
  for (int i = 0; i < 2; ++i)
    #pragma unroll
    for (int j = 0; j < 4; ++j) acc[i][j] = (f32x4){0.f, 0.f, 0.f, 0.f};
  const int y0g = yt * 2 - pd;                 // global row of LDS row 0
  for (int chunk = 0; chunk < nchunk; ++chunk) {
    __syncthreads();
    {
      const int nun = rows_in * pxw * 8;       // s16x8 units (max 2112)
      const int c0 = chunk * 64;
      #pragma unroll
      for (int i = 0; i < 3; ++i) {
        int e = t + i * 1024;
        if (e < nun) {
          int oct = e & 7;
          int pe = e >> 3;
          int pxs = pe % pxw;
          int row = pe / pxw;
          int yy = y0g + row, xx = pxs - pd;
          s16x8 v = {0, 0, 0, 0, 0, 0, 0, 0};
          if (yy >= 0 && yy < 64 && xx >= 0 && xx < 64)
            v = *(const s16x8*)(in + (size_t)((b * 64 + yy) * 64 + xx) * Cin
                                + c0 + oct * 8);
          *(s16x8*)(sl + (row * 66 + pxs) * 68 + oct * 8) = v;
        }
      }
    }
    __syncthreads();
    #pragma unroll 2
    for (int cb = 0; cb < 2; ++cb) {
      const int qc = chunk * 2 + cb;
      for (int dyi = 0; dyi < ndy; ++dyi) {
        const int lrow = wr + dyi;            // LDS row (wr+dy+pd)
        for (int dxi = 0; dxi < ndy; ++dxi) {
          const int tap = (taps == 9) ? dyi * 3 + dxi : 0;
          const int q = tap * ncb + qc;
          s16x8 afr[2];
          #pragma unroll
          for (int i = 0; i < 2; ++i) {
            int ot = wo * 2 + i;
            afr[i] = *(const s16x8*)(wf + (((size_t)q * 16 + ot) * 64 + l) * 8);
          }
          #pragma unroll
          for (int jt = 0; jt < 4; ++jt) {
            int pxi = jt * 16 + (l & 15) + dxi;   // dx+pd = dxi
            s16x8 bfr = *(const s16x8*)(sl + (lrow * 66 + pxi) * 68
                                        + cb * 32 + (l >> 4) * 8);
            #pragma unroll
            for (int i = 0; i < 2; ++i)
              acc[i][jt] = __builtin_amdgcn_mfma_f32_16x16x32_bf16(
                  afr[i], bfr, acc[i][jt], 0, 0, 0);
          }
        }
      }
    }
  }
  const int y = yt * 2 + wr;
  float ss[2] = {0.f, 0.f}, qq[2] = {0.f, 0.f};
  #pragma unroll
  for (int i = 0; i < 2; ++i) {
    #pragma unroll
    for (int jt = 0; jt < 4; ++jt) {
      int px = jt * 16 + (l & 15);
      int obase = wo * 32 + i * 16 + (l >> 4) * 4;
      size_t pbase = (size_t)((b * 64 + y) * 64 + px) * (remap ? 256 : Cout);
      if (!remap) {
        s16x4 r2;
        #pragma unroll
        for (int rr = 0; rr < 4; ++rr) {
          r2[rr] = f2bf(acc[i][jt][rr] + bias[obase + rr]);
          if (stats) { float v = bf2f(r2[rr]); ss[i] += v; qq[i] += v * v; }
        }
        *(s16x4*)(out + pbase + obase) = r2;
      } else {
        #pragma unroll
        for (int rr = 0; rr < 4; ++rr) {
          int o = obase + rr;
          if (o < Cout) {
            int op;
            if (o < 144) op = (o / 18) * 32 + (o % 18);
            else { int jj = o - 144; op = (jj / 9) * 32 + 18 + (jj % 9); }
            out[pbase + op] = f2bf(acc[i][jt][rr] + bias[o]);
          }
        }
      }
    }
  }
  if (stats && !remap) {
    // butterfly within each 32-lane half (lanes 0-31: ch-sub 0-7; 32-63: 8-15)
    #pragma unroll
    for (int i = 0; i < 2; ++i) {
      float s = ss[i], q = qq[i];
      #pragma unroll
      for (int m = 1; m <= 16; m <<= 1) {
        s += __shfl_xor(s, m);
        q += __shfl_xor(q, m);
      }
      if ((l & 31) == 0) {
        int gl = wo * 4 + i * 2 + (l >> 5);   // local group 0..31
        sred[wr][gl][0] = s;
        sred[wr][gl][1] = q;
      }
    }
    __syncthreads();
    if (t < 32) {
      float S = sred[0][t][0] + sred[1][t][0];
      float Q = sred[0][t][1] + sred[1][t][1];
      stats[(((size_t)b * 32 + t) << 5) + yt] = make_float2(S, Q);
    }
  }
}

// GroupNorm apply + SiLU: reduces np yt-partials of (b,g) in fixed order,
// applies to its 512 px x 8 ch slice in-place (bf16) + optional f32 NCHW out.
__global__ __launch_bounds__(256) void k_gn_apply(short* __restrict__ io,
    float* __restrict__ f32out, const float2* __restrict__ parts, int np,
    const float* __restrict__ gamma, const float* __restrict__ beta) {
  const int gid = blockIdx.x;
  const int b = gid & 7;
  const int r = gid >> 3;
  const int ck = r & 7, g = r >> 3;
  const int t = threadIdx.x;
  float S = 0.f, Q = 0.f;
  const float2* pp = parts + (((size_t)b * 32 + g) << 5);
  for (int i = 0; i < np; ++i) { float2 p = pp[i]; S += p.x; Q += p.y; }
  const float mean = S * (1.f / 32768.f);
  const float var = Q * (1.f / 32768.f) - mean * mean;
  const float rs = rsqrtf(var + 1e-6f);
  float ga[8], bb[8];
  #pragma unroll
  for (int j = 0; j < 8; ++j) {
    ga[j] = gamma[g * 8 + j] * rs;
    bb[j] = beta[g * 8 + j] - mean * ga[j];
  }
  #pragma unroll
  for (int i = 0; i < 2; ++i) {
    int e = ck * 512 + t + i * 256;
    short* ptr = io + (size_t)(b * 4096 + e) * 256 + g * 8;
    s16x8 v = *(const s16x8*)ptr;
    s16x8 r2;
    #pragma unroll
    for (int j = 0; j < 8; ++j) {
      float o = silu_f(bf2f(v[j]) * ga[j] + bb[j]);
      r2[j] = f2bf(o);
      if (f32out) f32out[(size_t)(b * 256 + g * 8 + j) * 4096 + e] = o;
    }
    *(s16x8*)ptr = r2;
  }
}

// depthwise 7x7 pad 3, NHWC bf16, LDS-staged, XCD-swizzled 1D grid.
// stats: per-(b,group,yt) {sum,sumsq} of stored output (wave = 1 group x 64 px).
__global__ __launch_bounds__(256) void k_dw7_nhwc(const short* __restrict__ in,
    const float* __restrict__ w, const float* __restrict__ bias,
    short* __restrict__ out, float2* __restrict__ stats) {
  const int gid = blockIdx.x;
  const int b = gid & 7;
  const int r = gid >> 3;
  const int ck = r & 7, yt = r >> 3;
  const int t = threadIdx.x;
  const int px = t & 63, oc = t >> 6;
  __shared__ __align__(16) short sl[10 * 70 * 40];
  __shared__ float wl[49 * 32];
  for (int e = t; e < 49 * 32; e += TPB) {
    int tap = e >> 5, cc = e & 31;
    wl[tap * 32 + cc] = w[(ck * 32 + cc) * 49 + tap];
  }
  const int y0in = yt * 4 - 3;
  #pragma unroll
  for (int i = 0; i < 11; ++i) {
    int e = t + i * TPB;
    if (e < 2800) {
      int oc2 = e & 3;
      int pe = e >> 2;
      int pxs = pe % 70;
      int row = pe / 70;
      int yy = y0in + row, xx = pxs - 3;
      s16x8 v = {0, 0, 0, 0, 0, 0, 0, 0};
      if (yy >= 0 && yy < 64 && xx >= 0 && xx < 64)
        v = *(const s16x8*)(in + (size_t)((b * 64 + yy) * 64 + xx) * 256
                            + ck * 32 + oc2 * 8);
      *(s16x8*)(sl + (row * 70 + pxs) * 40 + oc2 * 8) = v;
    }
  }
  __syncthreads();
  float acc[4][8];
  {
    float4 b0 = *(const float4*)(bias + ck * 32 + oc * 8);
    float4 b1 = *(const float4*)(bias + ck * 32 + oc * 8 + 4);
    #pragma unroll
    for (int r2 = 0; r2 < 4; ++r2) {
      acc[r2][0] = b0.x; acc[r2][1] = b0.y; acc[r2][2] = b0.z; acc[r2][3] = b0.w;
      acc[r2][4] = b1.x; acc[r2][5] = b1.y; acc[r2][6] = b1.z; acc[r2][7] = b1.w;
    }
  }
  #pragma unroll
  for (int ky = 0; ky < 7; ++ky) {
    #pragma unroll
    for (int kx = 0; kx < 7; ++kx) {
      const float4 w0 = *(const float4*)(wl + (ky * 7 + kx) * 32 + oc * 8);
      const float4 w1 = *(const float4*)(wl + (ky * 7 + kx) * 32 + oc * 8 + 4);
      #pragma unroll
      for (int r2 = 0; r2 < 4; ++r2) {
        s16x8 v = *(const s16x8*)(sl + ((r2 + ky) * 70 + (px + kx)) * 40 + oc * 8);
        acc[r2][0] += bf2f(v[0]) * w0.x; acc[r2][1] += bf2f(v[1]) * w0.y;
        acc[r2][2] += bf2f(v[2]) * w0.z; acc[r2][3] += bf2f(v[3]) * w0.w;
        acc[r2][4] += bf2f(v[4]) * w1.x; acc[r2][5] += bf2f(v[5]) * w1.y;
        acc[r2][6] += bf2f(v[6]) * w1.z; acc[r2][7] += bf2f(v[7]) * w1.w;
      }
    }
  }
  float ss = 0.f, qq = 0.f;
  #pragma unroll
  for (int r2 = 0; r2 < 4; ++r2) {
    int y = yt * 4 + r2;
    s16x8 o;
    #pragma unroll
    for (int j = 0; j < 8; ++j) {
      o[j] = f2bf(acc[r2][j]);
      float v = bf2f(o[j]);
      ss += v; qq += v * v;
    }
    *(s16x8*)(out + (size_t)((b * 64 + y) * 64 + px) * 256 + ck * 32 + oc * 8) = o;
  }
  // wave = one group (oc) x 64 px: full-wave butterfly, lane 0 writes.
  #pragma unroll
  for (int m = 1; m <= 32; m <<= 1) {
    ss += __shfl_xor(ss, m);
    qq += __shfl_xor(qq, m);
  }
  if ((t & 63) == 0)
    stats[(((size_t)b * 32 + ck * 4 + oc) << 5) + yt] = make_float2(ss, qq);
}

// Deformable conv v2 via MFMA, NHWC, px-split, XCD-swizzled (b = gid&7).
// Phase A: per-(px,k) bilinear weights/addresses once -> LDS table (9-stride).
// Phase B: gather+blend. Phase C: MFMA. (R19 verified, 134us.)
__global__ __launch_bounds__(256) void k_dcn_nhwc(const short* __restrict__ x,
    const short* __restrict__ co, const short* __restrict__ wf,
    const float* __restrict__ bias, float* __restrict__ out) {
  const int gid = blockIdx.x;
  const int b = gid & 7;
  const int r = gid >> 3;
  const int ph = r & 1, y = r >> 1;
  const int t = threadIdx.x;
  const int wid = t >> 6, l = t & 63;
  const int px0 = ph * 32;
  __shared__ __align__(16) short s2[9 * 32 * 40];
  __shared__ unsigned swt[288 * 9];   // [k*32+pxl]: w00..w11 (f32 bits), i00..i11
  f32x4 acc[4][2];
  #pragma unroll
  for (int i = 0; i < 4; ++i)
    #pragma unroll
    for (int j = 0; j < 2; ++j) acc[i][j] = (f32x4){0.f, 0.f, 0.f, 0.f};
  const short* xb = x + (size_t)b * 4096 * 256;
  for (int g = 0; g < 8; ++g) {
    __syncthreads();
    // phase A: 288 dense weight/address tasks (pxl, k)
    #pragma unroll
    for (int i = 0; i < 2; ++i) {
      int e2 = t + i * 256;
      if (e2 < 288) {
        int pxl = e2 & 31, k = e2 >> 5;
        int px = px0 + pxl;
        const short* cp = co + (size_t)(b * 4096 + y * 64 + px) * 256 + g * 32;
        float offy = bf2f(cp[2 * k]);
        float offx = bf2f(cp[2 * k + 1]);
        float mlog = bf2f(cp[18 + k]);
        float mv = 1.f / (1.f + __expf(-mlog));
        float py = offy + (float)(y - 1 + k / 3);
        float pxf = offx + (float)(px - 1 + k % 3);
        float y0f = floorf(py), x0f = floorf(pxf);
        float ly = py - y0f, lx = pxf - x0f;
        int y0 = (int)y0f, x0 = (int)x0f;
        int y1 = y0 + 1, x1 = x0 + 1;
        float fy0 = (y0 >= 0 && y0 < 64) ? 1.f : 0.f;
        float fy1 = (y1 >= 0 && y1 < 64) ? 1.f : 0.f;
        float fx0 = (x0 >= 0 && x0 < 64) ? 1.f : 0.f;
        float fx1 = (x1 >= 0 && x1 < 64) ? 1.f : 0.f;
        float w00 = (1.f - ly) * (1.f - lx) * fy0 * fx0 * mv;
        float w01 = (1.f - ly) * lx * fy0 * fx1 * mv;
        float w10 = ly * (1.f - lx) * fy1 * fx0 * mv;
        float w11 = ly * lx * fy1 * fx1 * mv;
        int y0c = min(63, max(0, y0)), y1c = min(63, max(0, y1));
        int x0c = min(63, max(0, x0)), x1c = min(63, max(0, x1));
        unsigned* wp = swt + e2 * 9;
        wp[0] = __float_as_uint(w00);
        wp[1] = __float_as_uint(w01);
        wp[2] = __float_as_uint(w10);
        wp[3] = __float_as_uint(w11);
        wp[4] = (unsigned)((y0c * 64 + x0c) * 256);
        wp[5] = (unsigned)((y0c * 64 + x1c) * 256);
        wp[6] = (unsigned)((y1c * 64 + x0c) * 256);
        wp[7] = (unsigned)((y1c * 64 + x1c) * 256);
      }
    }
    __syncthreads();
    // phase B: 1152 sampling tasks = 4 oct x 32 px x 9 k (gather + blend)
    #pragma unroll
    for (int i = 0; i < 5; ++i) {
      int e = t + i * 256;
      if (e < 1152) {
        int oct = e & 3, pxl = (e >> 2) & 31, k = e >> 7;
        const unsigned* wp = swt + (k * 32 + pxl) * 9;
        float w00 = __uint_as_float(wp[0]);
        float w01 = __uint_as_float(wp[1]);
        float w10 = __uint_as_float(wp[2]);
        float w11 = __uint_as_float(wp[3]);
        const short* xc = xb + g * 32 + oct * 8;
        s16x8 c00 = *(const s16x8*)(xc + wp[4]);
        s16x8 c01 = *(const s16x8*)(xc + wp[5]);
        s16x8 c10 = *(const s16x8*)(xc + wp[6]);
        s16x8 c11 = *(const s16x8*)(xc + wp[7]);
        s16x8 pk;
        #pragma unroll
        for (int cc = 0; cc < 8; ++cc) {
          float v = w00 * bf2f(c00[cc]) + w01 * bf2f(c01[cc])
                  + w10 * bf2f(c10[cc]) + w11 * bf2f(c11[cc]);
          pk[cc] = f2bf(v);
        }
        *(s16x8*)(s2 + (k * 32 + pxl) * 40 + oct * 8) = pk;
      }
    }
    __syncthreads();
    // phase C: MFMA (unchanged)
    #pragma unroll
    for (int k = 0; k < 9; ++k) {
      const int q = g * 9 + k;
      s16x8 afr[4], bfr[2];
      #pragma unroll
      for (int i = 0; i < 4; ++i)
        afr[i] = *(const s16x8*)(wf + (((size_t)q * 16 + wid * 4 + i) * 64 + l) * 8);
      #pragma unroll
      for (int jt = 0; jt < 2; ++jt)
        bfr[jt] = *(const s16x8*)(s2 + (k * 32 + jt * 16 + (l & 15)) * 40 + (l >> 4) * 8);
      #pragma unroll
      for (int i = 0; i < 4; ++i)
        #pragma unroll
        for (int jt = 0; jt < 2; ++jt)
          acc[i][jt] = __builtin_amdgcn_mfma_f32_16x16x32_bf16(
              afr[i], bfr[jt], acc[i][jt], 0, 0, 0);
    }
  }
  #pragma unroll
  for (int i = 0; i < 4; ++i) {
    int obase = wid * 64 + i * 16 + (l >> 4) * 4;
    #pragma unroll
    for (int jt = 0; jt < 2; ++jt) {
      int pxo = px0 + jt * 16 + (l & 15);
      #pragma unroll
      for (int rr = 0; rr < 4; ++rr) {
        int o = obase + rr;
        out[(((size_t)b * 256 + o) * 64 + y) * 64 + pxo] = acc[i][jt][rr] + bias[o];
      }
    }
  }
}

extern "C" void kernel_launch(void* const* d_in, const int* in_sizes, int n_in,
                              void* d_out, int out_size, void* d_ws, size_t ws_size,
                              hipStream_t stream) {
  const float* main_f = (const float*)d_in[0];
  const float* cond   = (const float*)d_in[1];
  const float* w1  = (const float*)d_in[2];
  const float* b1  = (const float*)d_in[3];
  const float* g1  = (const float*)d_in[4];
  const float* be1 = (const float*)d_in[5];
  const float* w2  = (const float*)d_in[6];
  const float* b2  = (const float*)d_in[7];
  const float* g2  = (const float*)d_in[8];
  const float* be2 = (const float*)d_in[9];
  const float* w3  = (const float*)d_in[10];
  const float* b3  = (const float*)d_in[11];
  const float* w4  = (const float*)d_in[12];
  const float* b4  = (const float*)d_in[13];
  const float* g3  = (const float*)d_in[14];
  const float* be3 = (const float*)d_in[15];
  const float* w_co  = (const float*)d_in[16];
  const float* b_co  = (const float*)d_in[17];
  const float* w_dcn = (const float*)d_in[18];
  const float* b_dcn = (const float*)d_in[19];

  float* out = (float*)d_out;
  float* warp_out = out;               // [8,256,64,64] f32 NCHW
  float* offset_feat = out + 8388608;  // [8,256,64,64] f32 NCHW

  short* ws = (short*)d_ws;
  short* bufA  = ws;                   // NHWC-512 conv1 input: 16777216
  short* Bb    = bufA + 16777216;      // NHWC-256: 8388608
  short* xbf   = Bb + 8388608;         // main NHWC-256 bf16: 8388608
  short* wfall = xbf + 8388608;        // contiguous: wf1 wf3 wf4 wfco wfdcn
  short* wf1   = wfall;                // 131072
  short* wf3   = wf1 + 131072;         // 65536
  short* wf4   = wf3 + 65536;          // 589824
  short* wfco  = wf4 + 589824;         // 589824
  short* wfdcn = wfco + 589824;        // 589824
  float2* parts2 = (float2*)(wfdcn + 589824);  // 8*32*32 float2 = 64KB

  auto cdiv = [](int a, int b) { return (a + b - 1) / b; };

  k_prep_all<<<cdiv(1966080, TPB), TPB, 0, stream>>>(w1, w3, w4, w_co, w_dcn, wfall);

  k_upsample_nhwc<<<cdiv(8 * 4096 * 256, TPB), TPB, 0, stream>>>(cond, bufA);
  dim3 gtr(64, 8, 8);
  k_main_tr<<<gtr, TPB, 0, stream>>>(main_f, xbf, bufA);

  // conv grids: 1D 256 blocks x 1024 threads, XCD-swizzled (b = gid&7)
  // conv1 (+GN1 stats in epilogue)
  k_conv2<<<256, 1024, 0, stream>>>(bufA, 512, 256, 1, wf1, b1, Bb, 0, parts2);
  k_gn_apply<<<2048, TPB, 0, stream>>>(Bb, nullptr, parts2, 32, g1, be1);
  // dw7 (+GN2 stats in epilogue, 16 yt-partials)
  k_dw7_nhwc<<<1024, TPB, 0, stream>>>(Bb, w2, b2, bufA, parts2);
  k_gn_apply<<<2048, TPB, 0, stream>>>(bufA, nullptr, parts2, 16, g2, be2);
  // conv3 (no stats)
  k_conv2<<<256, 1024, 0, stream>>>(bufA, 256, 256, 1, wf3, b3, Bb, 0, nullptr);
  // conv4 (+GN3 stats in epilogue)
  k_conv2<<<256, 1024, 0, stream>>>(Bb, 256, 256, 9, wf4, b4, bufA, 0, parts2);
  k_gn_apply<<<2048, TPB, 0, stream>>>(bufA, offset_feat, parts2, 32, g3, be3);
  // conv_offset: 3x3 256->216, channel-permuted NHWC-256 co (no stats)
  k_conv2<<<256, 1024, 0, stream>>>(bufA, 256, 216, 9, wfco, b_co, Bb, 1, nullptr);
  // deformable conv -> warp (output 0)
  k_dcn_nhwc<<<1024, TPB, 0, stream>>>(xbf, Bb, wfdcn, b_dcn, warp_out);
}